// Round 3
// baseline (364.891 us; speedup 1.0000x reference)
//
#include <hip/hip_runtime.h>
#include <hip/hip_bf16.h>

#define NB 2
#define NS 2048
#define NE 1024
#define NH 16
#define HD 64

typedef __hip_bfloat16 bf16;
typedef __attribute__((ext_vector_type(8))) short bf16x8;
typedef __attribute__((ext_vector_type(4))) float f32x4;

typedef __attribute__((address_space(3))) void* lds_p;
typedef const __attribute__((address_space(1))) void* glb_p;

#define MFMA16(a, b, c) __builtin_amdgcn_mfma_f32_16x16x32_bf16((a), (b), (c), 0, 0, 0)

__device__ __forceinline__ void gl_lds16(const void* g, void* l) {
    __builtin_amdgcn_global_load_lds((glb_p)g, (lds_p)l, 16, 0, 0);
}

__device__ __forceinline__ bf16x8 ldv8(const bf16* p) { return *(const bf16x8*)p; }

// ---------------- merged cast f32 -> bf16 (vectorized, 1 launch) ----------------
__global__ __launch_bounds__(256) void cast3_k(const float* __restrict__ x,
                                               const float* __restrict__ wqkv,
                                               const float* __restrict__ wo,
                                               bf16* __restrict__ xb,
                                               bf16* __restrict__ wqkvb,
                                               bf16* __restrict__ wob) {
    const int n_x = NB * NS * NE / 4;
    const int n_q = 3 * NE * NE / 4;
    const int n_o = NE * NE / 4;
    int i = blockIdx.x * 256 + threadIdx.x;
    const float* in;
    bf16* out;
    int j;
    if (i < n_x) {
        in = x; out = xb; j = i;
    } else if (i < n_x + n_q) {
        in = wqkv; out = wqkvb; j = i - n_x;
    } else if (i < n_x + n_q + n_o) {
        in = wo; out = wob; j = i - n_x - n_q;
    } else {
        return;
    }
    float4 v = ((const float4*)in)[j];
    union { ushort4 u; bf16 b[4]; } pk;
    pk.b[0] = __float2bfloat16(v.x);
    pk.b[1] = __float2bfloat16(v.y);
    pk.b[2] = __float2bfloat16(v.z);
    pk.b[3] = __float2bfloat16(v.w);
    ((ushort4*)out)[j] = pk.u;
}

// ---------------- QKV GEMM: C[t,f] = sum_e x[t,e] * Wqkv[f,e] + bqkv[f] ----------------
__global__ __launch_bounds__(256) void qkv_gemm(const bf16* __restrict__ A,
                                                const bf16* __restrict__ Bm,
                                                const float* __restrict__ bqkv,
                                                bf16* __restrict__ Qb, bf16* __restrict__ Kb,
                                                bf16* __restrict__ Vtb) {
    __shared__ bf16 As[128 * 32];
    __shared__ bf16 Bs[128 * 32];
    const int brow = blockIdx.x * 128;
    const int bcol = blockIdx.y * 128;
    const int t = threadIdx.x;
    const int w = t >> 6, lane = t & 63;
    const int wr = (w >> 1) * 64, wc = (w & 1) * 64;
    const int lr = lane & 15, lh = lane >> 4;
    const int K = 1024;

    f32x4 acc[4][4];
#pragma unroll
    for (int m = 0; m < 4; ++m)
#pragma unroll
        for (int n = 0; n < 4; ++n) acc[m][n] = (f32x4){0.f, 0.f, 0.f, 0.f};

    const bf16* ga0 = A + (size_t)(brow + (t >> 2)) * K + (t & 3) * 8;
    const bf16* ga1 = A + (size_t)(brow + 64 + (t >> 2)) * K + (t & 3) * 8;
    const bf16* gb0 = Bm + (size_t)(bcol + (t >> 2)) * K + (t & 3) * 8;
    const bf16* gb1 = Bm + (size_t)(bcol + 64 + (t >> 2)) * K + (t & 3) * 8;
    bf16* la0 = As + t * 8;
    bf16* la1 = As + 2048 + t * 8;
    bf16* lb0 = Bs + t * 8;
    bf16* lb1 = Bs + 2048 + t * 8;

    for (int kt = 0; kt < K; kt += 32) {
        gl_lds16(ga0 + kt, la0);
        gl_lds16(ga1 + kt, la1);
        gl_lds16(gb0 + kt, lb0);
        gl_lds16(gb1 + kt, lb1);
        __syncthreads();
        bf16x8 af[4], bfv[4];
#pragma unroll
        for (int m = 0; m < 4; ++m) af[m] = ldv8(&As[(wr + m * 16 + lr) * 32 + lh * 8]);
#pragma unroll
        for (int n = 0; n < 4; ++n) bfv[n] = ldv8(&Bs[(wc + n * 16 + lr) * 32 + lh * 8]);
#pragma unroll
        for (int m = 0; m < 4; ++m)
#pragma unroll
            for (int n = 0; n < 4; ++n) acc[m][n] = MFMA16(af[m], bfv[n], acc[m][n]);
        __syncthreads();
    }

    // epilogue: f -> (h, which, d); which: 0=Q 1=K 2=V
#pragma unroll
    for (int n = 0; n < 4; ++n) {
        const int col = bcol + wc + n * 16 + lr;
        const int h = col / 192;
        const int r = col - h * 192;
        const int wh = r >> 6;
        const int d = r & 63;
        const float bq = bqkv[col];
#pragma unroll
        for (int m = 0; m < 4; ++m) {
            const int row0 = brow + wr + m * 16 + lh * 4;  // token base; i adds 0..3
            const int b = row0 >> 11;
            const int s0 = row0 & 2047;
            const size_t hb = (size_t)(b * NH + h) * (NS * HD);
            if (wh == 2) {
                alignas(8) bf16 tmp[4];
#pragma unroll
                for (int i = 0; i < 4; ++i) tmp[i] = __float2bfloat16(acc[m][n][i] + bq);
                *(ushort4*)(Vtb + hb + (size_t)d * NS + s0) = *(const ushort4*)tmp;
            } else {
                bf16* dst = (wh == 0 ? Qb : Kb) + hb + (size_t)s0 * HD + d;
#pragma unroll
                for (int i = 0; i < 4; ++i) dst[(size_t)i * HD] = __float2bfloat16(acc[m][n][i] + bq);
            }
        }
    }
}

// ---------------- fused attention (swapped QK^T + register-dbuf bias) ----------------
// grid (S/64, B*H), block 256 = 4 independent waves, each owns 16 q-rows.
// mfma(K, Q) -> lane holds S[q=qw+(lane&15)][k=kt+n*16+(lane>>4)*4+i].
// Bias for tile kt+64 is loaded while tile kt computes (HBM-latency hiding).
__global__ __launch_bounds__(256, 4) void attn_k(const bf16* __restrict__ Qb,
                                                 const bf16* __restrict__ Kb,
                                                 const bf16* __restrict__ Vtb,
                                                 const float* __restrict__ bias,
                                                 bf16* __restrict__ valsb) {
    const int bh = blockIdx.y;
    const int q0 = blockIdx.x * 64;
    const int w = threadIdx.x >> 6, lane = threadIdx.x & 63;
    const int lr = lane & 15, lh = lane >> 4;
    __shared__ bf16 Ps[4][16][72];  // +8 pad

    const bf16* Qp = Qb + (size_t)bh * NS * HD;
    const bf16* Kp = Kb + (size_t)bh * NS * HD;
    const bf16* Vp = Vtb + (size_t)bh * HD * NS;

    const int qw = q0 + w * 16;
    bf16x8 qf0 = ldv8(&Qp[(qw + lr) * HD + lh * 8]);
    bf16x8 qf1 = ldv8(&Qp[(qw + lr) * HD + 32 + lh * 8]);

    // per-lane bias base: row q = qw+lr, col base lh*4
    const float* Bp = bias + (size_t)bh * NS * NS + (size_t)(qw + lr) * NS + lh * 4;

    f32x4 acc_o[4];
    float rowsum = 0.f;
#pragma unroll
    for (int n = 0; n < 4; ++n) acc_o[n] = (f32x4){0.f, 0.f, 0.f, 0.f};

    const float C1 = 0.18033688011112042f;  // 0.125 * log2(e)
    const float C2 = 7.2134752044448170f;   // 5 * log2(e)

    // prologue: bias tile 0 into registers
    float4 bv[4];
#pragma unroll
    for (int n = 0; n < 4; ++n) bv[n] = *(const float4*)(Bp + n * 16);

    for (int kt = 0; kt < NS; kt += 64) {
        // prefetch next tile's bias (one full tile of latency hiding)
        float4 bvn[4];
        if (kt + 64 < NS) {
#pragma unroll
            for (int n = 0; n < 4; ++n) bvn[n] = *(const float4*)(Bp + kt + 64 + n * 16);
        }
#pragma unroll
        for (int n = 0; n < 4; ++n) {
            bf16x8 k0 = ldv8(&Kp[(kt + n * 16 + lr) * HD + lh * 8]);
            bf16x8 k1 = ldv8(&Kp[(kt + n * 16 + lr) * HD + 32 + lh * 8]);
            f32x4 s = (f32x4){0.f, 0.f, 0.f, 0.f};
            s = MFMA16(k0, qf0, s);
            s = MFMA16(k1, qf1, s);
            union { ushort4 u; bf16 b[4]; } pk;
#pragma unroll
            for (int i = 0; i < 4; ++i) {
                float bb = (i == 0 ? bv[n].x : i == 1 ? bv[n].y : i == 2 ? bv[n].z : bv[n].w);
                float xv = (s[i] + bb) * C1;
                xv = fminf(fmaxf(xv, -C2), C2);
                float p = exp2f(xv);
                rowsum += p;
                pk.b[i] = __float2bfloat16(p);
            }
            *(ushort4*)&Ps[w][lr][n * 16 + lh * 4] = pk.u;
        }
        bf16x8 pa0 = ldv8(&Ps[w][lr][lh * 8]);
        bf16x8 pa1 = ldv8(&Ps[w][lr][32 + lh * 8]);
#pragma unroll
        for (int n = 0; n < 4; ++n) {
            bf16x8 v0 = ldv8(&Vp[(size_t)(n * 16 + lr) * NS + kt + lh * 8]);
            bf16x8 v1 = ldv8(&Vp[(size_t)(n * 16 + lr) * NS + kt + 32 + lh * 8]);
            acc_o[n] = MFMA16(pa0, v0, acc_o[n]);
            acc_o[n] = MFMA16(pa1, v1, acc_o[n]);
        }
        if (kt + 64 < NS) {
#pragma unroll
            for (int n = 0; n < 4; ++n) bv[n] = bvn[n];
        }
    }

    // rowsum for q = qw + (lane&15): reduce over the 4 lh-groups
    rowsum += __shfl_xor(rowsum, 16, 64);
    rowsum += __shfl_xor(rowsum, 32, 64);
    // redistribute: output rows are q = qw + lh*4 + i (held at lane lh*4+i)
    float inv[4];
#pragma unroll
    for (int i = 0; i < 4; ++i) inv[i] = 1.0f / __shfl(rowsum, lh * 4 + i, 64);

    const int b = bh >> 4, h = bh & 15;
#pragma unroll
    for (int n = 0; n < 4; ++n) {
#pragma unroll
        for (int i = 0; i < 4; ++i) {
            const int qrow = qw + lh * 4 + i;
            valsb[(size_t)(b * NS + qrow) * NE + h * HD + n * 16 + lr] =
                __float2bfloat16(acc_o[n][i] * inv[i]);
        }
    }
}

// ---------------- out GEMM: 128x64 tiles (512 blocks = 2/CU) ----------------
__global__ __launch_bounds__(256) void out_gemm(const bf16* __restrict__ A,
                                                const bf16* __restrict__ Bm,
                                                const float* __restrict__ bo,
                                                float* __restrict__ out) {
    __shared__ bf16 As[128 * 32];
    __shared__ bf16 Bs[64 * 32];
    const int brow = blockIdx.x * 128;
    const int bcol = blockIdx.y * 64;
    const int t = threadIdx.x;
    const int w = t >> 6, lane = t & 63;
    const int wr = (w >> 1) * 64, wc = (w & 1) * 32;
    const int lr = lane & 15, lh = lane >> 4;
    const int K = 1024;

    f32x4 acc[4][2];
#pragma unroll
    for (int m = 0; m < 4; ++m)
#pragma unroll
        for (int n = 0; n < 2; ++n) acc[m][n] = (f32x4){0.f, 0.f, 0.f, 0.f};

    const bf16* ga0 = A + (size_t)(brow + (t >> 2)) * K + (t & 3) * 8;
    const bf16* ga1 = A + (size_t)(brow + 64 + (t >> 2)) * K + (t & 3) * 8;
    const bf16* gb0 = Bm + (size_t)(bcol + (t >> 2)) * K + (t & 3) * 8;
    bf16* la0 = As + t * 8;
    bf16* la1 = As + 2048 + t * 8;
    bf16* lb0 = Bs + t * 8;

    for (int kt = 0; kt < K; kt += 32) {
        gl_lds16(ga0 + kt, la0);
        gl_lds16(ga1 + kt, la1);
        gl_lds16(gb0 + kt, lb0);
        __syncthreads();
        bf16x8 af[4], bfv[2];
#pragma unroll
        for (int m = 0; m < 4; ++m) af[m] = ldv8(&As[(wr + m * 16 + lr) * 32 + lh * 8]);
#pragma unroll
        for (int n = 0; n < 2; ++n) bfv[n] = ldv8(&Bs[(wc + n * 16 + lr) * 32 + lh * 8]);
#pragma unroll
        for (int m = 0; m < 4; ++m)
#pragma unroll
            for (int n = 0; n < 2; ++n) acc[m][n] = MFMA16(af[m], bfv[n], acc[m][n]);
        __syncthreads();
    }

#pragma unroll
    for (int n = 0; n < 2; ++n) {
        const int col = bcol + wc + n * 16 + lr;
        const float bv = bo[col];
#pragma unroll
        for (int m = 0; m < 4; ++m) {
            const int row0 = brow + wr + m * 16 + lh * 4;
#pragma unroll
            for (int i = 0; i < 4; ++i) out[(size_t)(row0 + i) * NE + col] = acc[m][n][i] + bv;
        }
    }
}

extern "C" void kernel_launch(void* const* d_in, const int* in_sizes, int n_in,
                              void* d_out, int out_size, void* d_ws, size_t ws_size,
                              hipStream_t stream) {
    const float* x = (const float*)d_in[0];
    const float* attn_bias = (const float*)d_in[1];
    const float* Wqkv = (const float*)d_in[2];
    const float* bqkv = (const float*)d_in[3];
    const float* Wo = (const float*)d_in[4];
    const float* bo = (const float*)d_in[5];
    float* out = (float*)d_out;

    char* ws = (char*)d_ws;
    bf16* xb = (bf16*)(ws);                      // 8 MiB  [4096,1024]
    bf16* Wqkvb = (bf16*)(ws + (8u << 20));      // 6 MiB  [3072,1024]
    bf16* Wob = (bf16*)(ws + (14u << 20));       // 2 MiB  [1024,1024]
    bf16* Qb = (bf16*)(ws + (16u << 20));        // 8 MiB  [B,H,S,HD]
    bf16* Kb = (bf16*)(ws + (24u << 20));        // 8 MiB  [B,H,S,HD]
    bf16* Vtb = (bf16*)(ws + (32u << 20));       // 8 MiB  [B,H,HD,S]
    bf16* valsb = (bf16*)(ws + (40u << 20));     // 8 MiB  [B,S,H,HD]

    // merged casts (1 launch)
    cast3_k<<<8192, 256, 0, stream>>>(x, Wqkv, Wo, xb, Wqkvb, Wob);

    // QKV projection
    qkv_gemm<<<dim3(32, 24), 256, 0, stream>>>(xb, Wqkvb, bqkv, Qb, Kb, Vtb);

    // fused attention
    attn_k<<<dim3(NS / 64, NB * NH), 256, 0, stream>>>(Qb, Kb, Vtb, attn_bias, valsb);

    // output projection
    out_gemm<<<dim3(32, 16), 256, 0, stream>>>(valsb, Wob, bo, out);
}

// Round 4
// 357.148 us; speedup vs baseline: 1.0217x; 1.0217x over previous
//
#include <hip/hip_runtime.h>
#include <hip/hip_bf16.h>

#define NB 2
#define NS 2048
#define NE 1024
#define NH 16
#define HD 64

typedef __hip_bfloat16 bf16;
typedef __attribute__((ext_vector_type(8))) short bf16x8;
typedef __attribute__((ext_vector_type(4))) float f32x4;

typedef __attribute__((address_space(3))) void* lds_p;
typedef const __attribute__((address_space(1))) void* glb_p;

#define MFMA16(a, b, c) __builtin_amdgcn_mfma_f32_16x16x32_bf16((a), (b), (c), 0, 0, 0)

__device__ __forceinline__ void gl_lds16(const void* g, void* l) {
    __builtin_amdgcn_global_load_lds((glb_p)g, (lds_p)l, 16, 0, 0);
}

__device__ __forceinline__ bf16x8 ldv8(const bf16* p) { return *(const bf16x8*)p; }

__device__ __forceinline__ float bf16raw2f(unsigned short v) {
    union { unsigned u; float f; } c;
    c.u = ((unsigned)v) << 16;
    return c.f;
}

// ---------------- merged cast f32 -> bf16 (vectorized, 1 launch) ----------------
__global__ __launch_bounds__(256) void cast3_k(const float* __restrict__ x,
                                               const float* __restrict__ wqkv,
                                               const float* __restrict__ wo,
                                               bf16* __restrict__ xb,
                                               bf16* __restrict__ wqkvb,
                                               bf16* __restrict__ wob) {
    const int n_x = NB * NS * NE / 4;
    const int n_q = 3 * NE * NE / 4;
    const int n_o = NE * NE / 4;
    int i = blockIdx.x * 256 + threadIdx.x;
    const float* in;
    bf16* out;
    int j;
    if (i < n_x) {
        in = x; out = xb; j = i;
    } else if (i < n_x + n_q) {
        in = wqkv; out = wqkvb; j = i - n_x;
    } else if (i < n_x + n_q + n_o) {
        in = wo; out = wob; j = i - n_x - n_q;
    } else {
        return;
    }
    float4 v = ((const float4*)in)[j];
    union { ushort4 u; bf16 b[4]; } pk;
    pk.b[0] = __float2bfloat16(v.x);
    pk.b[1] = __float2bfloat16(v.y);
    pk.b[2] = __float2bfloat16(v.z);
    pk.b[3] = __float2bfloat16(v.w);
    ((ushort4*)out)[j] = pk.u;
}

// ---------------- QKV GEMM: C[t,f] = sum_e x[t,e] * Wqkv[f,e] + bqkv[f] ----------------
__global__ __launch_bounds__(256) void qkv_gemm(const bf16* __restrict__ A,
                                                const bf16* __restrict__ Bm,
                                                const float* __restrict__ bqkv,
                                                bf16* __restrict__ Qb, bf16* __restrict__ Kb,
                                                bf16* __restrict__ Vtb) {
    __shared__ bf16 As[128 * 32];
    __shared__ bf16 Bs[128 * 32];
    const int brow = blockIdx.x * 128;
    const int bcol = blockIdx.y * 128;
    const int t = threadIdx.x;
    const int w = t >> 6, lane = t & 63;
    const int wr = (w >> 1) * 64, wc = (w & 1) * 64;
    const int lr = lane & 15, lh = lane >> 4;
    const int K = 1024;

    f32x4 acc[4][4];
#pragma unroll
    for (int m = 0; m < 4; ++m)
#pragma unroll
        for (int n = 0; n < 4; ++n) acc[m][n] = (f32x4){0.f, 0.f, 0.f, 0.f};

    const bf16* ga0 = A + (size_t)(brow + (t >> 2)) * K + (t & 3) * 8;
    const bf16* ga1 = A + (size_t)(brow + 64 + (t >> 2)) * K + (t & 3) * 8;
    const bf16* gb0 = Bm + (size_t)(bcol + (t >> 2)) * K + (t & 3) * 8;
    const bf16* gb1 = Bm + (size_t)(bcol + 64 + (t >> 2)) * K + (t & 3) * 8;
    bf16* la0 = As + t * 8;
    bf16* la1 = As + 2048 + t * 8;
    bf16* lb0 = Bs + t * 8;
    bf16* lb1 = Bs + 2048 + t * 8;

    for (int kt = 0; kt < K; kt += 32) {
        gl_lds16(ga0 + kt, la0);
        gl_lds16(ga1 + kt, la1);
        gl_lds16(gb0 + kt, lb0);
        gl_lds16(gb1 + kt, lb1);
        __syncthreads();
        bf16x8 af[4], bfv[4];
#pragma unroll
        for (int m = 0; m < 4; ++m) af[m] = ldv8(&As[(wr + m * 16 + lr) * 32 + lh * 8]);
#pragma unroll
        for (int n = 0; n < 4; ++n) bfv[n] = ldv8(&Bs[(wc + n * 16 + lr) * 32 + lh * 8]);
#pragma unroll
        for (int m = 0; m < 4; ++m)
#pragma unroll
            for (int n = 0; n < 4; ++n) acc[m][n] = MFMA16(af[m], bfv[n], acc[m][n]);
        __syncthreads();
    }

    // epilogue: f -> (h, which, d); which: 0=Q 1=K 2=V
#pragma unroll
    for (int n = 0; n < 4; ++n) {
        const int col = bcol + wc + n * 16 + lr;
        const int h = col / 192;
        const int r = col - h * 192;
        const int wh = r >> 6;
        const int d = r & 63;
        const float bq = bqkv[col];
#pragma unroll
        for (int m = 0; m < 4; ++m) {
            const int row0 = brow + wr + m * 16 + lh * 4;  // token base; i adds 0..3
            const int b = row0 >> 11;
            const int s0 = row0 & 2047;
            const size_t hb = (size_t)(b * NH + h) * (NS * HD);
            if (wh == 2) {
                alignas(8) bf16 tmp[4];
#pragma unroll
                for (int i = 0; i < 4; ++i) tmp[i] = __float2bfloat16(acc[m][n][i] + bq);
                *(ushort4*)(Vtb + hb + (size_t)d * NS + s0) = *(const ushort4*)tmp;
            } else {
                bf16* dst = (wh == 0 ? Qb : Kb) + hb + (size_t)s0 * HD + d;
#pragma unroll
                for (int i = 0; i < 4; ++i) dst[(size_t)i * HD] = __float2bfloat16(acc[m][n][i] + bq);
            }
        }
    }
}

// ---------------- fused attention (row-contiguous 1KB bias staging) ----------------
// grid (S/64, B*H), block 256 = 4 independent waves, each owns 16 q-rows.
// mfma(K, Q) -> lane holds S[q=qw+(lane&15)][k=kt+n*16+(lane>>4)*4+i].
// Bias: per wave, per 256-k phase: 16 global_load_dwordx4 (each = one q-row x 1KB
// CONTIGUOUS -> DRAM activation-efficient), cvt to bf16, double-buffered in LDS.
// No barriers: buffers are per-wave private.
__global__ __launch_bounds__(256, 2) void attn_k(const bf16* __restrict__ Qb,
                                                 const bf16* __restrict__ Kb,
                                                 const bf16* __restrict__ Vtb,
                                                 const float* __restrict__ bias,
                                                 bf16* __restrict__ valsb) {
    const int bh = blockIdx.y;
    const int q0 = blockIdx.x * 64;
    const int w = threadIdx.x >> 6, lane = threadIdx.x & 63;
    const int lr = lane & 15, lh = lane >> 4;
    __shared__ bf16 Bls[4][2][16 * 264];  // per-wave bias dbuf: 16 rows x (256+8 pad)
    __shared__ bf16 Ps[4][16][72];        // +8 pad

    const bf16* Qp = Qb + (size_t)bh * NS * HD;
    const bf16* Kp = Kb + (size_t)bh * NS * HD;
    const bf16* Vp = Vtb + (size_t)bh * HD * NS;

    const int qw = q0 + w * 16;
    bf16x8 qf0 = ldv8(&Qp[(qw + lr) * HD + lh * 8]);
    bf16x8 qf1 = ldv8(&Qp[(qw + lr) * HD + 32 + lh * 8]);

    const float* Bbase = bias + (size_t)bh * NS * NS + (size_t)qw * NS;

    f32x4 acc_o[4];
    float rowsum = 0.f;
#pragma unroll
    for (int n = 0; n < 4; ++n) acc_o[n] = (f32x4){0.f, 0.f, 0.f, 0.f};

    const float C1 = 0.18033688011112042f;  // 0.125 * log2(e)
    const float C2 = 7.2134752044448170f;   // 5 * log2(e)

    float4 vr[16];
    // prologue: stage phase 0
#pragma unroll
    for (int r = 0; r < 16; ++r)
        vr[r] = *((const float4*)(Bbase + (size_t)r * NS) + lane);
#pragma unroll
    for (int r = 0; r < 16; ++r) {
        union { ushort4 u; bf16 b[4]; } pk;
        pk.b[0] = __float2bfloat16(vr[r].x);
        pk.b[1] = __float2bfloat16(vr[r].y);
        pk.b[2] = __float2bfloat16(vr[r].z);
        pk.b[3] = __float2bfloat16(vr[r].w);
        *(ushort4*)&Bls[w][0][r * 264 + lane * 4] = pk.u;
    }

    for (int p = 0; p < 8; ++p) {
        // issue next phase's row-contiguous loads (1KB each) before computing
        if (p < 7) {
#pragma unroll
            for (int r = 0; r < 16; ++r)
                vr[r] = *((const float4*)(Bbase + (size_t)r * NS + (p + 1) * 256) + lane);
        }
        const bf16* Bw = &Bls[w][p & 1][0];
#pragma unroll
        for (int tt = 0; tt < 4; ++tt) {
            const int kt = p * 256 + tt * 64;
#pragma unroll
            for (int n = 0; n < 4; ++n) {
                bf16x8 k0 = ldv8(&Kp[(kt + n * 16 + lr) * HD + lh * 8]);
                bf16x8 k1 = ldv8(&Kp[(kt + n * 16 + lr) * HD + 32 + lh * 8]);
                f32x4 s = (f32x4){0.f, 0.f, 0.f, 0.f};
                s = MFMA16(k0, qf0, s);
                s = MFMA16(k1, qf1, s);
                ushort4 bu = *(const ushort4*)&Bw[lr * 264 + tt * 64 + n * 16 + lh * 4];
                float bb[4] = {bf16raw2f(bu.x), bf16raw2f(bu.y), bf16raw2f(bu.z), bf16raw2f(bu.w)};
                union { ushort4 u; bf16 b[4]; } pk;
#pragma unroll
                for (int i = 0; i < 4; ++i) {
                    float xv = (s[i] + bb[i]) * C1;
                    xv = fminf(fmaxf(xv, -C2), C2);
                    float pr = exp2f(xv);
                    rowsum += pr;
                    pk.b[i] = __float2bfloat16(pr);
                }
                *(ushort4*)&Ps[w][lr][n * 16 + lh * 4] = pk.u;
            }
            bf16x8 pa0 = ldv8(&Ps[w][lr][lh * 8]);
            bf16x8 pa1 = ldv8(&Ps[w][lr][32 + lh * 8]);
#pragma unroll
            for (int n = 0; n < 4; ++n) {
                bf16x8 v0 = ldv8(&Vp[(size_t)(n * 16 + lr) * NS + kt + lh * 8]);
                bf16x8 v1 = ldv8(&Vp[(size_t)(n * 16 + lr) * NS + kt + 32 + lh * 8]);
                acc_o[n] = MFMA16(pa0, v0, acc_o[n]);
                acc_o[n] = MFMA16(pa1, v1, acc_o[n]);
            }
        }
        // write next phase's buffer (loads have had the whole phase to land)
        if (p < 7) {
#pragma unroll
            for (int r = 0; r < 16; ++r) {
                union { ushort4 u; bf16 b[4]; } pk;
                pk.b[0] = __float2bfloat16(vr[r].x);
                pk.b[1] = __float2bfloat16(vr[r].y);
                pk.b[2] = __float2bfloat16(vr[r].z);
                pk.b[3] = __float2bfloat16(vr[r].w);
                *(ushort4*)&Bls[w][(p + 1) & 1][r * 264 + lane * 4] = pk.u;
            }
        }
    }

    // rowsum for q = qw + (lane&15): reduce over the 4 lh-groups
    rowsum += __shfl_xor(rowsum, 16, 64);
    rowsum += __shfl_xor(rowsum, 32, 64);
    // redistribute: output rows are q = qw + lh*4 + i (held at lane lh*4+i)
    float inv[4];
#pragma unroll
    for (int i = 0; i < 4; ++i) inv[i] = 1.0f / __shfl(rowsum, lh * 4 + i, 64);

    const int b = bh >> 4, h = bh & 15;
#pragma unroll
    for (int n = 0; n < 4; ++n) {
#pragma unroll
        for (int i = 0; i < 4; ++i) {
            const int qrow = qw + lh * 4 + i;
            valsb[(size_t)(b * NS + qrow) * NE + h * HD + n * 16 + lr] =
                __float2bfloat16(acc_o[n][i] * inv[i]);
        }
    }
}

// ---------------- out GEMM: 128x64 tiles (512 blocks = 2/CU) ----------------
__global__ __launch_bounds__(256) void out_gemm(const bf16* __restrict__ A,
                                                const bf16* __restrict__ Bm,
                                                const float* __restrict__ bo,
                                                float* __restrict__ out) {
    __shared__ bf16 As[128 * 32];
    __shared__ bf16 Bs[64 * 32];
    const int brow = blockIdx.x * 128;
    const int bcol = blockIdx.y * 64;
    const int t = threadIdx.x;
    const int w = t >> 6, lane = t & 63;
    const int wr = (w >> 1) * 64, wc = (w & 1) * 32;
    const int lr = lane & 15, lh = lane >> 4;
    const int K = 1024;

    f32x4 acc[4][2];
#pragma unroll
    for (int m = 0; m < 4; ++m)
#pragma unroll
        for (int n = 0; n < 2; ++n) acc[m][n] = (f32x4){0.f, 0.f, 0.f, 0.f};

    const bf16* ga0 = A + (size_t)(brow + (t >> 2)) * K + (t & 3) * 8;
    const bf16* ga1 = A + (size_t)(brow + 64 + (t >> 2)) * K + (t & 3) * 8;
    const bf16* gb0 = Bm + (size_t)(bcol + (t >> 2)) * K + (t & 3) * 8;
    bf16* la0 = As + t * 8;
    bf16* la1 = As + 2048 + t * 8;
    bf16* lb0 = Bs + t * 8;

    for (int kt = 0; kt < K; kt += 32) {
        gl_lds16(ga0 + kt, la0);
        gl_lds16(ga1 + kt, la1);
        gl_lds16(gb0 + kt, lb0);
        __syncthreads();
        bf16x8 af[4], bfv[2];
#pragma unroll
        for (int m = 0; m < 4; ++m) af[m] = ldv8(&As[(wr + m * 16 + lr) * 32 + lh * 8]);
#pragma unroll
        for (int n = 0; n < 2; ++n) bfv[n] = ldv8(&Bs[(wc + n * 16 + lr) * 32 + lh * 8]);
#pragma unroll
        for (int m = 0; m < 4; ++m)
#pragma unroll
            for (int n = 0; n < 2; ++n) acc[m][n] = MFMA16(af[m], bfv[n], acc[m][n]);
        __syncthreads();
    }

#pragma unroll
    for (int n = 0; n < 2; ++n) {
        const int col = bcol + wc + n * 16 + lr;
        const float bv = bo[col];
#pragma unroll
        for (int m = 0; m < 4; ++m) {
            const int row0 = brow + wr + m * 16 + lh * 4;
#pragma unroll
            for (int i = 0; i < 4; ++i) out[(size_t)(row0 + i) * NE + col] = acc[m][n][i] + bv;
        }
    }
}

extern "C" void kernel_launch(void* const* d_in, const int* in_sizes, int n_in,
                              void* d_out, int out_size, void* d_ws, size_t ws_size,
                              hipStream_t stream) {
    const float* x = (const float*)d_in[0];
    const float* attn_bias = (const float*)d_in[1];
    const float* Wqkv = (const float*)d_in[2];
    const float* bqkv = (const float*)d_in[3];
    const float* Wo = (const float*)d_in[4];
    const float* bo = (const float*)d_in[5];
    float* out = (float*)d_out;

    char* ws = (char*)d_ws;
    bf16* xb = (bf16*)(ws);                      // 8 MiB  [4096,1024]
    bf16* Wqkvb = (bf16*)(ws + (8u << 20));      // 6 MiB  [3072,1024]
    bf16* Wob = (bf16*)(ws + (14u << 20));       // 2 MiB  [1024,1024]
    bf16* Qb = (bf16*)(ws + (16u << 20));        // 8 MiB  [B,H,S,HD]
    bf16* Kb = (bf16*)(ws + (24u << 20));        // 8 MiB  [B,H,S,HD]
    bf16* Vtb = (bf16*)(ws + (32u << 20));       // 8 MiB  [B,H,HD,S]
    bf16* valsb = (bf16*)(ws + (40u << 20));     // 8 MiB  [B,S,H,HD]

    // merged casts (1 launch)
    cast3_k<<<8192, 256, 0, stream>>>(x, Wqkv, Wo, xb, Wqkvb, Wob);

    // QKV projection
    qkv_gemm<<<dim3(32, 24), 256, 0, stream>>>(xb, Wqkvb, bqkv, Qb, Kb, Vtb);

    // fused attention
    attn_k<<<dim3(NS / 64, NB * NH), 256, 0, stream>>>(Qb, Kb, Vtb, attn_bias, valsb);

    // output projection
    out_gemm<<<dim3(32, 16), 256, 0, stream>>>(valsb, Wob, bo, out);
}

// Round 5
// 355.533 us; speedup vs baseline: 1.0263x; 1.0045x over previous
//
#include <hip/hip_runtime.h>
#include <hip/hip_bf16.h>

#define NB 2
#define NS 2048
#define NE 1024
#define NH 16
#define HD 64

typedef __hip_bfloat16 bf16;
typedef __attribute__((ext_vector_type(8))) short bf16x8;
typedef __attribute__((ext_vector_type(4))) float f32x4;

typedef __attribute__((address_space(3))) void* lds_p;
typedef const __attribute__((address_space(1))) void* glb_p;

#define MFMA16(a, b, c) __builtin_amdgcn_mfma_f32_16x16x32_bf16((a), (b), (c), 0, 0, 0)

__device__ __forceinline__ void gl_lds16(const void* g, void* l) {
    __builtin_amdgcn_global_load_lds((glb_p)g, (lds_p)l, 16, 0, 0);
}

__device__ __forceinline__ bf16x8 ldv8(const bf16* p) { return *(const bf16x8*)p; }

// ---------------- merged cast f32 -> bf16 (vectorized, 1 launch) ----------------
__global__ __launch_bounds__(256) void cast3_k(const float* __restrict__ x,
                                               const float* __restrict__ wqkv,
                                               const float* __restrict__ wo,
                                               bf16* __restrict__ xb,
                                               bf16* __restrict__ wqkvb,
                                               bf16* __restrict__ wob) {
    const int n_x = NB * NS * NE / 4;
    const int n_q = 3 * NE * NE / 4;
    const int n_o = NE * NE / 4;
    int i = blockIdx.x * 256 + threadIdx.x;
    const float* in;
    bf16* out;
    int j;
    if (i < n_x) {
        in = x; out = xb; j = i;
    } else if (i < n_x + n_q) {
        in = wqkv; out = wqkvb; j = i - n_x;
    } else if (i < n_x + n_q + n_o) {
        in = wo; out = wob; j = i - n_x - n_q;
    } else {
        return;
    }
    float4 v = ((const float4*)in)[j];
    union { ushort4 u; bf16 b[4]; } pk;
    pk.b[0] = __float2bfloat16(v.x);
    pk.b[1] = __float2bfloat16(v.y);
    pk.b[2] = __float2bfloat16(v.z);
    pk.b[3] = __float2bfloat16(v.w);
    ((ushort4*)out)[j] = pk.u;
}

// ---------------- QKV GEMM: C[t,f] = sum_e x[t,e] * Wqkv[f,e] + bqkv[f] ----------------
__global__ __launch_bounds__(256) void qkv_gemm(const bf16* __restrict__ A,
                                                const bf16* __restrict__ Bm,
                                                const float* __restrict__ bqkv,
                                                bf16* __restrict__ Qb, bf16* __restrict__ Kb,
                                                bf16* __restrict__ Vtb) {
    __shared__ bf16 As[128 * 32];
    __shared__ bf16 Bs[128 * 32];
    const int brow = blockIdx.x * 128;
    const int bcol = blockIdx.y * 128;
    const int t = threadIdx.x;
    const int w = t >> 6, lane = t & 63;
    const int wr = (w >> 1) * 64, wc = (w & 1) * 64;
    const int lr = lane & 15, lh = lane >> 4;
    const int K = 1024;

    f32x4 acc[4][4];
#pragma unroll
    for (int m = 0; m < 4; ++m)
#pragma unroll
        for (int n = 0; n < 4; ++n) acc[m][n] = (f32x4){0.f, 0.f, 0.f, 0.f};

    const bf16* ga0 = A + (size_t)(brow + (t >> 2)) * K + (t & 3) * 8;
    const bf16* ga1 = A + (size_t)(brow + 64 + (t >> 2)) * K + (t & 3) * 8;
    const bf16* gb0 = Bm + (size_t)(bcol + (t >> 2)) * K + (t & 3) * 8;
    const bf16* gb1 = Bm + (size_t)(bcol + 64 + (t >> 2)) * K + (t & 3) * 8;
    bf16* la0 = As + t * 8;
    bf16* la1 = As + 2048 + t * 8;
    bf16* lb0 = Bs + t * 8;
    bf16* lb1 = Bs + 2048 + t * 8;

    for (int kt = 0; kt < K; kt += 32) {
        gl_lds16(ga0 + kt, la0);
        gl_lds16(ga1 + kt, la1);
        gl_lds16(gb0 + kt, lb0);
        gl_lds16(gb1 + kt, lb1);
        __syncthreads();
        bf16x8 af[4], bfv[4];
#pragma unroll
        for (int m = 0; m < 4; ++m) af[m] = ldv8(&As[(wr + m * 16 + lr) * 32 + lh * 8]);
#pragma unroll
        for (int n = 0; n < 4; ++n) bfv[n] = ldv8(&Bs[(wc + n * 16 + lr) * 32 + lh * 8]);
#pragma unroll
        for (int m = 0; m < 4; ++m)
#pragma unroll
            for (int n = 0; n < 4; ++n) acc[m][n] = MFMA16(af[m], bfv[n], acc[m][n]);
        __syncthreads();
    }

    // epilogue: f -> (h, which, d); which: 0=Q 1=K 2=V
#pragma unroll
    for (int n = 0; n < 4; ++n) {
        const int col = bcol + wc + n * 16 + lr;
        const int h = col / 192;
        const int r = col - h * 192;
        const int wh = r >> 6;
        const int d = r & 63;
        const float bq = bqkv[col];
#pragma unroll
        for (int m = 0; m < 4; ++m) {
            const int row0 = brow + wr + m * 16 + lh * 4;  // token base; i adds 0..3
            const int b = row0 >> 11;
            const int s0 = row0 & 2047;
            const size_t hb = (size_t)(b * NH + h) * (NS * HD);
            if (wh == 2) {
                alignas(8) bf16 tmp[4];
#pragma unroll
                for (int i = 0; i < 4; ++i) tmp[i] = __float2bfloat16(acc[m][n][i] + bq);
                *(ushort4*)(Vtb + hb + (size_t)d * NS + s0) = *(const ushort4*)tmp;
            } else {
                bf16* dst = (wh == 0 ? Qb : Kb) + hb + (size_t)s0 * HD + d;
#pragma unroll
                for (int i = 0; i < 4; ++i) dst[(size_t)i * HD] = __float2bfloat16(acc[m][n][i] + bq);
            }
        }
    }
}

// ---------------- fused attention (XCD-swizzled: per-XCD L2-resident K/V) ----------------
// 1-D grid of 1024 blocks. Block L -> XCD L%8 (round-robin dispatch). Swizzle so each
// XCD owns 4 bh values: its resident K/V working set = 4 x 512KB = 2MB <= 4MB L2.
// Per block: 4 independent waves x 16 q-rows. mfma(K,Q): lane holds
// S[q=qw+(lane&15)][k=kt+(lane>>4)*4+i+n*16]. K regs prefetched 1 tile ahead;
// bias f32 register double-buffered 1 tile ahead.
__global__ __launch_bounds__(256, 4) void attn_k(const bf16* __restrict__ Qb,
                                                 const bf16* __restrict__ Kb,
                                                 const bf16* __restrict__ Vtb,
                                                 const float* __restrict__ bias,
                                                 bf16* __restrict__ valsb) {
    const int L = blockIdx.x;
    const int xcd = L & 7, kk = L >> 3;
    const int bh = (xcd << 2) | (kk >> 5);   // 4 bh per XCD
    const int q0 = (kk & 31) * 64;
    const int w = threadIdx.x >> 6, lane = threadIdx.x & 63;
    const int lr = lane & 15, lh = lane >> 4;
    __shared__ bf16 Ps[4][16][72];  // +8 pad

    const bf16* Qp = Qb + (size_t)bh * NS * HD;
    const bf16* Kp = Kb + (size_t)bh * NS * HD;
    const bf16* Vp = Vtb + (size_t)bh * HD * NS;

    const int qw = q0 + w * 16;
    bf16x8 qf0 = ldv8(&Qp[(qw + lr) * HD + lh * 8]);
    bf16x8 qf1 = ldv8(&Qp[(qw + lr) * HD + 32 + lh * 8]);

    // per-lane bias base: row q = qw+lr, col base lh*4
    const float* Bp = bias + (size_t)bh * NS * NS + (size_t)(qw + lr) * NS + lh * 4;

    f32x4 acc_o[4];
    float rowsum = 0.f;
#pragma unroll
    for (int n = 0; n < 4; ++n) acc_o[n] = (f32x4){0.f, 0.f, 0.f, 0.f};

    const float C1 = 0.18033688011112042f;  // 0.125 * log2(e)
    const float C2 = 7.2134752044448170f;   // 5 * log2(e)

    // prologue: K tile 0 + bias tile 0 into registers
    bf16x8 kr[8];
#pragma unroll
    for (int n = 0; n < 4; ++n) {
        kr[2 * n] = ldv8(&Kp[(n * 16 + lr) * HD + lh * 8]);
        kr[2 * n + 1] = ldv8(&Kp[(n * 16 + lr) * HD + 32 + lh * 8]);
    }
    float4 bv[4];
#pragma unroll
    for (int n = 0; n < 4; ++n) bv[n] = *(const float4*)(Bp + n * 16);

    for (int kt = 0; kt < NS; kt += 64) {
        // QK^T from prefetched K registers
        f32x4 s[4];
#pragma unroll
        for (int n = 0; n < 4; ++n) {
            s[n] = (f32x4){0.f, 0.f, 0.f, 0.f};
            s[n] = MFMA16(kr[2 * n], qf0, s[n]);
            s[n] = MFMA16(kr[2 * n + 1], qf1, s[n]);
        }
        // prefetch next tile's K + bias (in flight during exp + PV below)
        float4 bvn[4];
        if (kt + 64 < NS) {
#pragma unroll
            for (int n = 0; n < 4; ++n) {
                kr[2 * n] = ldv8(&Kp[(kt + 64 + n * 16 + lr) * HD + lh * 8]);
                kr[2 * n + 1] = ldv8(&Kp[(kt + 64 + n * 16 + lr) * HD + 32 + lh * 8]);
                bvn[n] = *(const float4*)(Bp + kt + 64 + n * 16);
            }
        }
        // softmax numerator (clip bounds it: no max-tracking)
#pragma unroll
        for (int n = 0; n < 4; ++n) {
            union { ushort4 u; bf16 b[4]; } pk;
#pragma unroll
            for (int i = 0; i < 4; ++i) {
                float bb = (i == 0 ? bv[n].x : i == 1 ? bv[n].y : i == 2 ? bv[n].z : bv[n].w);
                float xv = (s[n][i] + bb) * C1;
                xv = fminf(fmaxf(xv, -C2), C2);
                float p = exp2f(xv);
                rowsum += p;
                pk.b[i] = __float2bfloat16(p);
            }
            *(ushort4*)&Ps[w][lr][n * 16 + lh * 4] = pk.u;
        }
        bf16x8 pa0 = ldv8(&Ps[w][lr][lh * 8]);
        bf16x8 pa1 = ldv8(&Ps[w][lr][32 + lh * 8]);
#pragma unroll
        for (int n = 0; n < 4; ++n) {
            bf16x8 v0 = ldv8(&Vp[(size_t)(n * 16 + lr) * NS + kt + lh * 8]);
            bf16x8 v1 = ldv8(&Vp[(size_t)(n * 16 + lr) * NS + kt + 32 + lh * 8]);
            acc_o[n] = MFMA16(pa0, v0, acc_o[n]);
            acc_o[n] = MFMA16(pa1, v1, acc_o[n]);
        }
        if (kt + 64 < NS) {
#pragma unroll
            for (int n = 0; n < 4; ++n) bv[n] = bvn[n];
        }
    }

    // rowsum for q = qw + (lane&15): reduce over the 4 lh-groups
    rowsum += __shfl_xor(rowsum, 16, 64);
    rowsum += __shfl_xor(rowsum, 32, 64);
    // redistribute: output rows are q = qw + lh*4 + i (held at lane lh*4+i)
    float inv[4];
#pragma unroll
    for (int i = 0; i < 4; ++i) inv[i] = 1.0f / __shfl(rowsum, lh * 4 + i, 64);

    const int b = bh >> 4, h = bh & 15;
#pragma unroll
    for (int n = 0; n < 4; ++n) {
#pragma unroll
        for (int i = 0; i < 4; ++i) {
            const int qrow = qw + lh * 4 + i;
            valsb[(size_t)(b * NS + qrow) * NE + h * HD + n * 16 + lr] =
                __float2bfloat16(acc_o[n][i] * inv[i]);
        }
    }
}

// ---------------- out GEMM: 128x64 tiles (512 blocks = 2/CU) ----------------
__global__ __launch_bounds__(256) void out_gemm(const bf16* __restrict__ A,
                                                const bf16* __restrict__ Bm,
                                                const float* __restrict__ bo,
                                                float* __restrict__ out) {
    __shared__ bf16 As[128 * 32];
    __shared__ bf16 Bs[64 * 32];
    const int brow = blockIdx.x * 128;
    const int bcol = blockIdx.y * 64;
    const int t = threadIdx.x;
    const int w = t >> 6, lane = t & 63;
    const int wr = (w >> 1) * 64, wc = (w & 1) * 32;
    const int lr = lane & 15, lh = lane >> 4;
    const int K = 1024;

    f32x4 acc[4][2];
#pragma unroll
    for (int m = 0; m < 4; ++m)
#pragma unroll
        for (int n = 0; n < 2; ++n) acc[m][n] = (f32x4){0.f, 0.f, 0.f, 0.f};

    const bf16* ga0 = A + (size_t)(brow + (t >> 2)) * K + (t & 3) * 8;
    const bf16* ga1 = A + (size_t)(brow + 64 + (t >> 2)) * K + (t & 3) * 8;
    const bf16* gb0 = Bm + (size_t)(bcol + (t >> 2)) * K + (t & 3) * 8;
    bf16* la0 = As + t * 8;
    bf16* la1 = As + 2048 + t * 8;
    bf16* lb0 = Bs + t * 8;

    for (int kt = 0; kt < K; kt += 32) {
        gl_lds16(ga0 + kt, la0);
        gl_lds16(ga1 + kt, la1);
        gl_lds16(gb0 + kt, lb0);
        __syncthreads();
        bf16x8 af[4], bfv[2];
#pragma unroll
        for (int m = 0; m < 4; ++m) af[m] = ldv8(&As[(wr + m * 16 + lr) * 32 + lh * 8]);
#pragma unroll
        for (int n = 0; n < 2; ++n) bfv[n] = ldv8(&Bs[(wc + n * 16 + lr) * 32 + lh * 8]);
#pragma unroll
        for (int m = 0; m < 4; ++m)
#pragma unroll
            for (int n = 0; n < 2; ++n) acc[m][n] = MFMA16(af[m], bfv[n], acc[m][n]);
        __syncthreads();
    }

#pragma unroll
    for (int n = 0; n < 2; ++n) {
        const int col = bcol + wc + n * 16 + lr;
        const float bv = bo[col];
#pragma unroll
        for (int m = 0; m < 4; ++m) {
            const int row0 = brow + wr + m * 16 + lh * 4;
#pragma unroll
            for (int i = 0; i < 4; ++i) out[(size_t)(row0 + i) * NE + col] = acc[m][n][i] + bv;
        }
    }
}

extern "C" void kernel_launch(void* const* d_in, const int* in_sizes, int n_in,
                              void* d_out, int out_size, void* d_ws, size_t ws_size,
                              hipStream_t stream) {
    const float* x = (const float*)d_in[0];
    const float* attn_bias = (const float*)d_in[1];
    const float* Wqkv = (const float*)d_in[2];
    const float* bqkv = (const float*)d_in[3];
    const float* Wo = (const float*)d_in[4];
    const float* bo = (const float*)d_in[5];
    float* out = (float*)d_out;

    char* ws = (char*)d_ws;
    bf16* xb = (bf16*)(ws);                      // 8 MiB  [4096,1024]
    bf16* Wqkvb = (bf16*)(ws + (8u << 20));      // 6 MiB  [3072,1024]
    bf16* Wob = (bf16*)(ws + (14u << 20));       // 2 MiB  [1024,1024]
    bf16* Qb = (bf16*)(ws + (16u << 20));        // 8 MiB  [B,H,S,HD]
    bf16* Kb = (bf16*)(ws + (24u << 20));        // 8 MiB  [B,H,S,HD]
    bf16* Vtb = (bf16*)(ws + (32u << 20));       // 8 MiB  [B,H,HD,S]
    bf16* valsb = (bf16*)(ws + (40u << 20));     // 8 MiB  [B,S,H,HD]

    // merged casts (1 launch)
    cast3_k<<<8192, 256, 0, stream>>>(x, Wqkv, Wo, xb, Wqkvb, Wob);

    // QKV projection
    qkv_gemm<<<dim3(32, 24), 256, 0, stream>>>(xb, Wqkvb, bqkv, Qb, Kb, Vtb);

    // fused attention (1-D grid, XCD swizzle inside)
    attn_k<<<dim3(1024), 256, 0, stream>>>(Qb, Kb, Vtb, attn_bias, valsb);

    // output projection
    out_gemm<<<dim3(32, 16), 256, 0, stream>>>(valsb, Wob, bo, out);
}

// Round 6
// 276.310 us; speedup vs baseline: 1.3206x; 1.2867x over previous
//
#include <hip/hip_runtime.h>
#include <hip/hip_bf16.h>

#define NB 2
#define NS 2048
#define NE 1024
#define NH 16
#define HD 64

typedef __hip_bfloat16 bf16;
typedef __attribute__((ext_vector_type(8))) short bf16x8;
typedef __attribute__((ext_vector_type(4))) float f32x4;

typedef __attribute__((address_space(3))) void* lds_p;
typedef const __attribute__((address_space(1))) void* glb_p;

#define MFMA16(a, b, c) __builtin_amdgcn_mfma_f32_16x16x32_bf16((a), (b), (c), 0, 0, 0)

__device__ __forceinline__ void gl_lds16(const void* g, void* l) {
    __builtin_amdgcn_global_load_lds((glb_p)g, (lds_p)l, 16, 0, 0);
}

__device__ __forceinline__ bf16x8 ldv8(const bf16* p) { return *(const bf16x8*)p; }

// ---------------- merged cast f32 -> bf16 (vectorized, 1 launch) ----------------
__global__ __launch_bounds__(256) void cast3_k(const float* __restrict__ x,
                                               const float* __restrict__ wqkv,
                                               const float* __restrict__ wo,
                                               bf16* __restrict__ xb,
                                               bf16* __restrict__ wqkvb,
                                               bf16* __restrict__ wob) {
    const int n_x = NB * NS * NE / 4;
    const int n_q = 3 * NE * NE / 4;
    const int n_o = NE * NE / 4;
    int i = blockIdx.x * 256 + threadIdx.x;
    const float* in;
    bf16* out;
    int j;
    if (i < n_x) {
        in = x; out = xb; j = i;
    } else if (i < n_x + n_q) {
        in = wqkv; out = wqkvb; j = i - n_x;
    } else if (i < n_x + n_q + n_o) {
        in = wo; out = wob; j = i - n_x - n_q;
    } else {
        return;
    }
    float4 v = ((const float4*)in)[j];
    union { ushort4 u; bf16 b[4]; } pk;
    pk.b[0] = __float2bfloat16(v.x);
    pk.b[1] = __float2bfloat16(v.y);
    pk.b[2] = __float2bfloat16(v.z);
    pk.b[3] = __float2bfloat16(v.w);
    ((ushort4*)out)[j] = pk.u;
}

// ---------------- QKV GEMM: C[t,f] = sum_e x[t,e] * Wqkv[f,e] + bqkv[f] ----------------
__global__ __launch_bounds__(256) void qkv_gemm(const bf16* __restrict__ A,
                                                const bf16* __restrict__ Bm,
                                                const float* __restrict__ bqkv,
                                                bf16* __restrict__ Qb, bf16* __restrict__ Kb,
                                                bf16* __restrict__ Vtb) {
    __shared__ bf16 As[128 * 32];
    __shared__ bf16 Bs[128 * 32];
    const int brow = blockIdx.x * 128;
    const int bcol = blockIdx.y * 128;
    const int t = threadIdx.x;
    const int w = t >> 6, lane = t & 63;
    const int wr = (w >> 1) * 64, wc = (w & 1) * 64;
    const int lr = lane & 15, lh = lane >> 4;
    const int K = 1024;

    f32x4 acc[4][4];
#pragma unroll
    for (int m = 0; m < 4; ++m)
#pragma unroll
        for (int n = 0; n < 4; ++n) acc[m][n] = (f32x4){0.f, 0.f, 0.f, 0.f};

    const bf16* ga0 = A + (size_t)(brow + (t >> 2)) * K + (t & 3) * 8;
    const bf16* ga1 = A + (size_t)(brow + 64 + (t >> 2)) * K + (t & 3) * 8;
    const bf16* gb0 = Bm + (size_t)(bcol + (t >> 2)) * K + (t & 3) * 8;
    const bf16* gb1 = Bm + (size_t)(bcol + 64 + (t >> 2)) * K + (t & 3) * 8;
    bf16* la0 = As + t * 8;
    bf16* la1 = As + 2048 + t * 8;
    bf16* lb0 = Bs + t * 8;
    bf16* lb1 = Bs + 2048 + t * 8;

    for (int kt = 0; kt < K; kt += 32) {
        gl_lds16(ga0 + kt, la0);
        gl_lds16(ga1 + kt, la1);
        gl_lds16(gb0 + kt, lb0);
        gl_lds16(gb1 + kt, lb1);
        __syncthreads();
        bf16x8 af[4], bfv[4];
#pragma unroll
        for (int m = 0; m < 4; ++m) af[m] = ldv8(&As[(wr + m * 16 + lr) * 32 + lh * 8]);
#pragma unroll
        for (int n = 0; n < 4; ++n) bfv[n] = ldv8(&Bs[(wc + n * 16 + lr) * 32 + lh * 8]);
#pragma unroll
        for (int m = 0; m < 4; ++m)
#pragma unroll
            for (int n = 0; n < 4; ++n) acc[m][n] = MFMA16(af[m], bfv[n], acc[m][n]);
        __syncthreads();
    }

    // epilogue: f -> (h, which, d); which: 0=Q 1=K 2=V
#pragma unroll
    for (int n = 0; n < 4; ++n) {
        const int col = bcol + wc + n * 16 + lr;
        const int h = col / 192;
        const int r = col - h * 192;
        const int wh = r >> 6;
        const int d = r & 63;
        const float bq = bqkv[col];
#pragma unroll
        for (int m = 0; m < 4; ++m) {
            const int row0 = brow + wr + m * 16 + lh * 4;  // token base; i adds 0..3
            const int b = row0 >> 11;
            const int s0 = row0 & 2047;
            const size_t hb = (size_t)(b * NH + h) * (NS * HD);
            if (wh == 2) {
                alignas(8) bf16 tmp[4];
#pragma unroll
                for (int i = 0; i < 4; ++i) tmp[i] = __float2bfloat16(acc[m][n][i] + bq);
                *(ushort4*)(Vtb + hb + (size_t)d * NS + s0) = *(const ushort4*)tmp;
            } else {
                bf16* dst = (wh == 0 ? Qb : Kb) + hb + (size_t)s0 * HD + d;
#pragma unroll
                for (int i = 0; i < 4; ++i) dst[(size_t)i * HD] = __float2bfloat16(acc[m][n][i] + bq);
            }
        }
    }
}

// ---------------- fused attention: block-shared LDS K/V (MSHR relief) ----------------
// 1024 blocks (XCD swizzle), 4 waves x 16 q-rows, one bh per block.
// K,V tiles [64x64] staged ONCE per block via global_load_lds (dbuf, XOR-swizzled
// both-sides per rule #21: pre-swizzled global src, linear DMA dest, swizzled ds_read).
// Cuts per-CU K/V line-requests 4x so the HBM bias stream gets the request pool.
// Bias: per-wave f32 float4, register double-buffered.
__global__ __launch_bounds__(256, 3) void attn_k(const bf16* __restrict__ Qb,
                                                 const bf16* __restrict__ Kb,
                                                 const bf16* __restrict__ Vtb,
                                                 const float* __restrict__ bias,
                                                 bf16* __restrict__ valsb) {
    const int L = blockIdx.x;
    const int xcd = L & 7, kk = L >> 3;
    const int bh = (xcd << 2) | (kk >> 5);   // 4 bh per XCD
    const int q0 = (kk & 31) * 64;
    const int t = threadIdx.x;
    const int w = t >> 6, lane = t & 63;
    const int lr = lane & 15, lh = lane >> 4;

    __shared__ bf16 Kls[2][64 * 64];
    __shared__ bf16 Vls[2][64 * 64];
    __shared__ bf16 Ps[4][16][72];  // +8 pad

    const bf16* Qp = Qb + (size_t)bh * NS * HD;
    const bf16* Kp = Kb + (size_t)bh * NS * HD;
    const bf16* Vp = Vtb + (size_t)bh * HD * NS;

    const int qw = q0 + w * 16;
    bf16x8 qf0 = ldv8(&Qp[(qw + lr) * HD + lh * 8]);
    bf16x8 qf1 = ldv8(&Qp[(qw + lr) * HD + 32 + lh * 8]);

    // per-lane bias base: row q = qw+lr, col base lh*4
    const float* Bp = bias + (size_t)bh * NS * NS + (size_t)(qw + lr) * NS + lh * 4;

    // staging geometry: thread t, round j in {0,1}: row = t/8 + j*32,
    // data col-elems = ((t&7)*8) ^ ((row&7)<<3); LDS dest linear = (t + j*256)*8 elems.
    const int srow0 = t >> 3;
    const int sce0 = ((t & 7) * 8) ^ ((srow0 & 7) << 3);
    const int srow1 = srow0 + 32;
    const int sce1 = ((t & 7) * 8) ^ ((srow1 & 7) << 3);

    f32x4 acc_o[4];
    float rowsum = 0.f;
#pragma unroll
    for (int n = 0; n < 4; ++n) acc_o[n] = (f32x4){0.f, 0.f, 0.f, 0.f};

    const float C1 = 0.18033688011112042f;  // 0.125 * log2(e)
    const float C2 = 7.2134752044448170f;   // 5 * log2(e)

    // prologue: bias tile 0 regs + stage K/V tile 0 into buf 0
    float4 bv[4];
#pragma unroll
    for (int n = 0; n < 4; ++n) bv[n] = *(const float4*)(Bp + n * 16);

    gl_lds16(Kp + (size_t)srow0 * HD + sce0, &Kls[0][t * 8]);
    gl_lds16(Kp + (size_t)srow1 * HD + sce1, &Kls[0][2048 + t * 8]);
    gl_lds16(Vp + (size_t)srow0 * NS + sce0, &Vls[0][t * 8]);
    gl_lds16(Vp + (size_t)srow1 * NS + sce1, &Vls[0][2048 + t * 8]);
    __syncthreads();

    // read-side swizzled column offsets (row = n*16+lr => row&7 = lr&7)
    const int rswz = (lr & 7) << 3;
    const int ce0 = (lh * 8) ^ rswz;        // k-half 0
    const int ce1 = (32 + lh * 8) ^ rswz;   // k-half 1

    for (int tt = 0; tt < 32; ++tt) {
        const int cur = tt & 1;
        // issue next tile's bias (HBM, longest latency) first
        float4 bvn[4];
        if (tt < 31) {
            const int ktn = (tt + 1) * 64;
#pragma unroll
            for (int n = 0; n < 4; ++n) bvn[n] = *(const float4*)(Bp + ktn + n * 16);
            // then next tile's K/V staging (L2-ish)
            gl_lds16(Kp + (size_t)(ktn + srow0) * HD + sce0, &Kls[cur ^ 1][t * 8]);
            gl_lds16(Kp + (size_t)(ktn + srow1) * HD + sce1, &Kls[cur ^ 1][2048 + t * 8]);
            gl_lds16(Vp + (size_t)srow0 * NS + ktn + sce0, &Vls[cur ^ 1][t * 8]);
            gl_lds16(Vp + (size_t)srow1 * NS + ktn + sce1, &Vls[cur ^ 1][2048 + t * 8]);
        }
        // QK^T from LDS
        const bf16* Kc = &Kls[cur][0];
        f32x4 s[4];
#pragma unroll
        for (int n = 0; n < 4; ++n) {
            bf16x8 k0 = ldv8(&Kc[(n * 16 + lr) * 64 + ce0]);
            bf16x8 k1 = ldv8(&Kc[(n * 16 + lr) * 64 + ce1]);
            s[n] = (f32x4){0.f, 0.f, 0.f, 0.f};
            s[n] = MFMA16(k0, qf0, s[n]);
            s[n] = MFMA16(k1, qf1, s[n]);
        }
        // softmax numerator (clip bounds it: no max tracking)
#pragma unroll
        for (int n = 0; n < 4; ++n) {
            union { ushort4 u; bf16 b[4]; } pk;
#pragma unroll
            for (int i = 0; i < 4; ++i) {
                float bb = (i == 0 ? bv[n].x : i == 1 ? bv[n].y : i == 2 ? bv[n].z : bv[n].w);
                float xv = (s[n][i] + bb) * C1;
                xv = fminf(fmaxf(xv, -C2), C2);
                float p = exp2f(xv);
                rowsum += p;
                pk.b[i] = __float2bfloat16(p);
            }
            *(ushort4*)&Ps[w][lr][n * 16 + lh * 4] = pk.u;
        }
        bf16x8 pa0 = ldv8(&Ps[w][lr][lh * 8]);
        bf16x8 pa1 = ldv8(&Ps[w][lr][32 + lh * 8]);
        // PV from LDS
        const bf16* Vc = &Vls[cur][0];
#pragma unroll
        for (int n = 0; n < 4; ++n) {
            bf16x8 v0 = ldv8(&Vc[(n * 16 + lr) * 64 + ce0]);
            bf16x8 v1 = ldv8(&Vc[(n * 16 + lr) * 64 + ce1]);
            acc_o[n] = MFMA16(pa0, v0, acc_o[n]);
            acc_o[n] = MFMA16(pa1, v1, acc_o[n]);
        }
        if (tt < 31) {
#pragma unroll
            for (int n = 0; n < 4; ++n) bv[n] = bvn[n];
        }
        __syncthreads();  // next buffer staged + all reads of it done
    }

    // rowsum for q = qw + (lane&15): reduce over the 4 lh-groups
    rowsum += __shfl_xor(rowsum, 16, 64);
    rowsum += __shfl_xor(rowsum, 32, 64);
    // redistribute: output rows are q = qw + lh*4 + i (held at lane lh*4+i)
    float inv[4];
#pragma unroll
    for (int i = 0; i < 4; ++i) inv[i] = 1.0f / __shfl(rowsum, lh * 4 + i, 64);

    const int b = bh >> 4, h = bh & 15;
#pragma unroll
    for (int n = 0; n < 4; ++n) {
#pragma unroll
        for (int i = 0; i < 4; ++i) {
            const int qrow = qw + lh * 4 + i;
            valsb[(size_t)(b * NS + qrow) * NE + h * HD + n * 16 + lr] =
                __float2bfloat16(acc_o[n][i] * inv[i]);
        }
    }
}

// ---------------- out GEMM: 128x64 tiles (512 blocks = 2/CU) ----------------
__global__ __launch_bounds__(256) void out_gemm(const bf16* __restrict__ A,
                                                const bf16* __restrict__ Bm,
                                                const float* __restrict__ bo,
                                                float* __restrict__ out) {
    __shared__ bf16 As[128 * 32];
    __shared__ bf16 Bs[64 * 32];
    const int brow = blockIdx.x * 128;
    const int bcol = blockIdx.y * 64;
    const int t = threadIdx.x;
    const int w = t >> 6, lane = t & 63;
    const int wr = (w >> 1) * 64, wc = (w & 1) * 32;
    const int lr = lane & 15, lh = lane >> 4;
    const int K = 1024;

    f32x4 acc[4][2];
#pragma unroll
    for (int m = 0; m < 4; ++m)
#pragma unroll
        for (int n = 0; n < 2; ++n) acc[m][n] = (f32x4){0.f, 0.f, 0.f, 0.f};

    const bf16* ga0 = A + (size_t)(brow + (t >> 2)) * K + (t & 3) * 8;
    const bf16* ga1 = A + (size_t)(brow + 64 + (t >> 2)) * K + (t & 3) * 8;
    const bf16* gb0 = Bm + (size_t)(bcol + (t >> 2)) * K + (t & 3) * 8;
    bf16* la0 = As + t * 8;
    bf16* la1 = As + 2048 + t * 8;
    bf16* lb0 = Bs + t * 8;

    for (int kt = 0; kt < K; kt += 32) {
        gl_lds16(ga0 + kt, la0);
        gl_lds16(ga1 + kt, la1);
        gl_lds16(gb0 + kt, lb0);
        __syncthreads();
        bf16x8 af[4], bfv[2];
#pragma unroll
        for (int m = 0; m < 4; ++m) af[m] = ldv8(&As[(wr + m * 16 + lr) * 32 + lh * 8]);
#pragma unroll
        for (int n = 0; n < 2; ++n) bfv[n] = ldv8(&Bs[(wc + n * 16 + lr) * 32 + lh * 8]);
#pragma unroll
        for (int m = 0; m < 4; ++m)
#pragma unroll
            for (int n = 0; n < 2; ++n) acc[m][n] = MFMA16(af[m], bfv[n], acc[m][n]);
        __syncthreads();
    }

#pragma unroll
    for (int n = 0; n < 2; ++n) {
        const int col = bcol + wc + n * 16 + lr;
        const float bv = bo[col];
#pragma unroll
        for (int m = 0; m < 4; ++m) {
            const int row0 = brow + wr + m * 16 + lh * 4;
#pragma unroll
            for (int i = 0; i < 4; ++i) out[(size_t)(row0 + i) * NE + col] = acc[m][n][i] + bv;
        }
    }
}

extern "C" void kernel_launch(void* const* d_in, const int* in_sizes, int n_in,
                              void* d_out, int out_size, void* d_ws, size_t ws_size,
                              hipStream_t stream) {
    const float* x = (const float*)d_in[0];
    const float* attn_bias = (const float*)d_in[1];
    const float* Wqkv = (const float*)d_in[2];
    const float* bqkv = (const float*)d_in[3];
    const float* Wo = (const float*)d_in[4];
    const float* bo = (const float*)d_in[5];
    float* out = (float*)d_out;

    char* ws = (char*)d_ws;
    bf16* xb = (bf16*)(ws);                      // 8 MiB  [4096,1024]
    bf16* Wqkvb = (bf16*)(ws + (8u << 20));      // 6 MiB  [3072,1024]
    bf16* Wob = (bf16*)(ws + (14u << 20));       // 2 MiB  [1024,1024]
    bf16* Qb = (bf16*)(ws + (16u << 20));        // 8 MiB  [B,H,S,HD]
    bf16* Kb = (bf16*)(ws + (24u << 20));        // 8 MiB  [B,H,S,HD]
    bf16* Vtb = (bf16*)(ws + (32u << 20));       // 8 MiB  [B,H,HD,S]
    bf16* valsb = (bf16*)(ws + (40u << 20));     // 8 MiB  [B,S,H,HD]

    // merged casts (1 launch)
    cast3_k<<<8192, 256, 0, stream>>>(x, Wqkv, Wo, xb, Wqkvb, Wob);

    // QKV projection
    qkv_gemm<<<dim3(32, 24), 256, 0, stream>>>(xb, Wqkvb, bqkv, Qb, Kb, Vtb);

    // fused attention (1-D grid, XCD swizzle inside)
    attn_k<<<dim3(1024), 256, 0, stream>>>(Qb, Kb, Vtb, attn_bias, valsb);

    // output projection
    out_gemm<<<dim3(32, 16), 256, 0, stream>>>(valsb, Wob, bo, out);
}

// Round 7
// 245.444 us; speedup vs baseline: 1.4867x; 1.1258x over previous
//
#include <hip/hip_runtime.h>
#include <hip/hip_bf16.h>

#define NB 2
#define NS 2048
#define NE 1024
#define NH 16
#define HD 64

typedef __hip_bfloat16 bf16;
typedef __attribute__((ext_vector_type(8))) short bf16x8;
typedef __attribute__((ext_vector_type(4))) float f32x4;

typedef __attribute__((address_space(3))) void* lds_p;
typedef const __attribute__((address_space(1))) void* glb_p;

#define MFMA16(a, b, c) __builtin_amdgcn_mfma_f32_16x16x32_bf16((a), (b), (c), 0, 0, 0)

__device__ __forceinline__ void gl_lds16(const void* g, void* l) {
    __builtin_amdgcn_global_load_lds((glb_p)g, (lds_p)l, 16, 0, 0);
}

__device__ __forceinline__ bf16x8 ldv8(const bf16* p) { return *(const bf16x8*)p; }

// ---------------- merged cast f32 -> bf16 (vectorized, 1 launch) ----------------
__global__ __launch_bounds__(256) void cast3_k(const float* __restrict__ x,
                                               const float* __restrict__ wqkv,
                                               const float* __restrict__ wo,
                                               bf16* __restrict__ xb,
                                               bf16* __restrict__ wqkvb,
                                               bf16* __restrict__ wob) {
    const int n_x = NB * NS * NE / 4;
    const int n_q = 3 * NE * NE / 4;
    const int n_o = NE * NE / 4;
    int i = blockIdx.x * 256 + threadIdx.x;
    const float* in;
    bf16* out;
    int j;
    if (i < n_x) {
        in = x; out = xb; j = i;
    } else if (i < n_x + n_q) {
        in = wqkv; out = wqkvb; j = i - n_x;
    } else if (i < n_x + n_q + n_o) {
        in = wo; out = wob; j = i - n_x - n_q;
    } else {
        return;
    }
    float4 v = ((const float4*)in)[j];
    union { ushort4 u; bf16 b[4]; } pk;
    pk.b[0] = __float2bfloat16(v.x);
    pk.b[1] = __float2bfloat16(v.y);
    pk.b[2] = __float2bfloat16(v.z);
    pk.b[3] = __float2bfloat16(v.w);
    ((ushort4*)out)[j] = pk.u;
}

// ---------------- QKV GEMM: C[t,f] = sum_e x[t,e] * Wqkv[f,e] + bqkv[f] ----------------
__global__ __launch_bounds__(256) void qkv_gemm(const bf16* __restrict__ A,
                                                const bf16* __restrict__ Bm,
                                                const float* __restrict__ bqkv,
                                                bf16* __restrict__ Qb, bf16* __restrict__ Kb,
                                                bf16* __restrict__ Vtb) {
    __shared__ bf16 As[128 * 32];
    __shared__ bf16 Bs[128 * 32];
    const int brow = blockIdx.x * 128;
    const int bcol = blockIdx.y * 128;
    const int t = threadIdx.x;
    const int w = t >> 6, lane = t & 63;
    const int wr = (w >> 1) * 64, wc = (w & 1) * 64;
    const int lr = lane & 15, lh = lane >> 4;
    const int K = 1024;

    f32x4 acc[4][4];
#pragma unroll
    for (int m = 0; m < 4; ++m)
#pragma unroll
        for (int n = 0; n < 4; ++n) acc[m][n] = (f32x4){0.f, 0.f, 0.f, 0.f};

    const bf16* ga0 = A + (size_t)(brow + (t >> 2)) * K + (t & 3) * 8;
    const bf16* ga1 = A + (size_t)(brow + 64 + (t >> 2)) * K + (t & 3) * 8;
    const bf16* gb0 = Bm + (size_t)(bcol + (t >> 2)) * K + (t & 3) * 8;
    const bf16* gb1 = Bm + (size_t)(bcol + 64 + (t >> 2)) * K + (t & 3) * 8;
    bf16* la0 = As + t * 8;
    bf16* la1 = As + 2048 + t * 8;
    bf16* lb0 = Bs + t * 8;
    bf16* lb1 = Bs + 2048 + t * 8;

    for (int kt = 0; kt < K; kt += 32) {
        gl_lds16(ga0 + kt, la0);
        gl_lds16(ga1 + kt, la1);
        gl_lds16(gb0 + kt, lb0);
        gl_lds16(gb1 + kt, lb1);
        __syncthreads();
        bf16x8 af[4], bfv[4];
#pragma unroll
        for (int m = 0; m < 4; ++m) af[m] = ldv8(&As[(wr + m * 16 + lr) * 32 + lh * 8]);
#pragma unroll
        for (int n = 0; n < 4; ++n) bfv[n] = ldv8(&Bs[(wc + n * 16 + lr) * 32 + lh * 8]);
#pragma unroll
        for (int m = 0; m < 4; ++m)
#pragma unroll
            for (int n = 0; n < 4; ++n) acc[m][n] = MFMA16(af[m], bfv[n], acc[m][n]);
        __syncthreads();
    }

    // epilogue: f -> (h, which, d); which: 0=Q 1=K 2=V
#pragma unroll
    for (int n = 0; n < 4; ++n) {
        const int col = bcol + wc + n * 16 + lr;
        const int h = col / 192;
        const int r = col - h * 192;
        const int wh = r >> 6;
        const int d = r & 63;
        const float bq = bqkv[col];
#pragma unroll
        for (int m = 0; m < 4; ++m) {
            const int row0 = brow + wr + m * 16 + lh * 4;  // token base; i adds 0..3
            const int b = row0 >> 11;
            const int s0 = row0 & 2047;
            const size_t hb = (size_t)(b * NH + h) * (NS * HD);
            if (wh == 2) {
                alignas(8) bf16 tmp[4];
#pragma unroll
                for (int i = 0; i < 4; ++i) tmp[i] = __float2bfloat16(acc[m][n][i] + bq);
                *(ushort4*)(Vtb + hb + (size_t)d * NS + s0) = *(const ushort4*)tmp;
            } else {
                bf16* dst = (wh == 0 ? Qb : Kb) + hb + (size_t)s0 * HD + d;
#pragma unroll
                for (int i = 0; i < 4; ++i) dst[(size_t)i * HD] = __float2bfloat16(acc[m][n][i] + bq);
            }
        }
    }
}

// ---------------- fused attention: LDS K/V + counted-vmcnt pipeline (T4) ----------------
// 1024 blocks (XCD swizzle), 4 waves x 16 q-rows, one bh per block.
// Per tile, pinned issue order: [gl_lds(tt+1) x4] | [bias(tt+2) x4] | compute(tt) |
// s_waitcnt vmcnt(4) | s_barrier.  The 4 newest ops at the barrier are bias(tt+2),
// so gl_lds(tt+1) is complete (cross-wave LDS visibility), while the bias HBM
// stream stays 2 tiles deep and is NEVER drained (no __syncthreads vmcnt(0)).
__global__ __launch_bounds__(256, 3) void attn_k(const bf16* __restrict__ Qb,
                                                 const bf16* __restrict__ Kb,
                                                 const bf16* __restrict__ Vtb,
                                                 const float* __restrict__ bias,
                                                 bf16* __restrict__ valsb) {
    const int L = blockIdx.x;
    const int xcd = L & 7, kk = L >> 3;
    const int bh = (xcd << 2) | (kk >> 5);   // 4 bh per XCD (K/V L2-resident)
    const int q0 = (kk & 31) * 64;
    const int t = threadIdx.x;
    const int w = t >> 6, lane = t & 63;
    const int lr = lane & 15, lh = lane >> 4;

    __shared__ bf16 Kls[2][64 * 64];
    __shared__ bf16 Vls[2][64 * 64];
    __shared__ bf16 Ps[4][16][72];  // +8 pad, wave-private

    const bf16* Qp = Qb + (size_t)bh * NS * HD;
    const bf16* Kp = Kb + (size_t)bh * NS * HD;
    const bf16* Vp = Vtb + (size_t)bh * HD * NS;

    const int qw = q0 + w * 16;
    bf16x8 qf0 = ldv8(&Qp[(qw + lr) * HD + lh * 8]);
    bf16x8 qf1 = ldv8(&Qp[(qw + lr) * HD + 32 + lh * 8]);

    // per-lane bias base: row q = qw+lr, col base lh*4
    const float* Bp = bias + (size_t)bh * NS * NS + (size_t)(qw + lr) * NS + lh * 4;

    // staging geometry (XOR-swizzled source, linear LDS dest; rule #21)
    const int srow0 = t >> 3;
    const int sce0 = ((t & 7) * 8) ^ ((srow0 & 7) << 3);
    const int srow1 = srow0 + 32;
    const int sce1 = ((t & 7) * 8) ^ ((srow1 & 7) << 3);

    f32x4 acc_o[4];
    float rowsum = 0.f;
#pragma unroll
    for (int n = 0; n < 4; ++n) acc_o[n] = (f32x4){0.f, 0.f, 0.f, 0.f};

    const float C1 = 0.18033688011112042f;  // 0.125 * log2(e)
    const float C2 = 7.2134752044448170f;   // 5 * log2(e)

    // read-side swizzled column offsets (row = n*16+lr => row&7 = lr&7)
    const int rswz = (lr & 7) << 3;
    const int ce0 = (lh * 8) ^ rswz;
    const int ce1 = (32 + lh * 8) ^ rswz;

    // -------- prologue: [gl_lds(0) x4] | [bias(0) x4] | [bias(1) x4] | vmcnt(8) | bar
    gl_lds16(Kp + (size_t)srow0 * HD + sce0, &Kls[0][t * 8]);
    gl_lds16(Kp + (size_t)srow1 * HD + sce1, &Kls[0][2048 + t * 8]);
    gl_lds16(Vp + (size_t)srow0 * NS + sce0, &Vls[0][t * 8]);
    gl_lds16(Vp + (size_t)srow1 * NS + sce1, &Vls[0][2048 + t * 8]);
    __builtin_amdgcn_sched_barrier(0);
    float4 bv0[4], bv1[4], bv2[4];
#pragma unroll
    for (int n = 0; n < 4; ++n) bv0[n] = *(const float4*)(Bp + n * 16);
    __builtin_amdgcn_sched_barrier(0);
#pragma unroll
    for (int n = 0; n < 4; ++n) bv1[n] = *(const float4*)(Bp + 64 + n * 16);
    __builtin_amdgcn_sched_barrier(0);
    asm volatile("s_waitcnt vmcnt(8)" ::: "memory");
    __builtin_amdgcn_sched_barrier(0);
    __builtin_amdgcn_s_barrier();
    __builtin_amdgcn_sched_barrier(0);

#define ATTN_COMPUTE(CUR)                                                             \
    {                                                                                 \
        const bf16* Kc = &Kls[CUR][0];                                                \
        f32x4 s[4];                                                                   \
        _Pragma("unroll") for (int n = 0; n < 4; ++n) {                               \
            bf16x8 k0 = ldv8(&Kc[(n * 16 + lr) * 64 + ce0]);                          \
            bf16x8 k1 = ldv8(&Kc[(n * 16 + lr) * 64 + ce1]);                          \
            s[n] = (f32x4){0.f, 0.f, 0.f, 0.f};                                       \
            s[n] = MFMA16(k0, qf0, s[n]);                                             \
            s[n] = MFMA16(k1, qf1, s[n]);                                             \
        }                                                                             \
        _Pragma("unroll") for (int n = 0; n < 4; ++n) {                               \
            union { ushort4 u; bf16 b[4]; } pk;                                       \
            _Pragma("unroll") for (int i = 0; i < 4; ++i) {                           \
                float bb = (i == 0   ? bv0[n].x                                       \
                            : i == 1 ? bv0[n].y                                       \
                            : i == 2 ? bv0[n].z                                       \
                                     : bv0[n].w);                                     \
                float xv = (s[n][i] + bb) * C1;                                       \
                xv = fminf(fmaxf(xv, -C2), C2);                                       \
                float p = exp2f(xv);                                                  \
                rowsum += p;                                                          \
                pk.b[i] = __float2bfloat16(p);                                        \
            }                                                                         \
            *(ushort4*)&Ps[w][lr][n * 16 + lh * 4] = pk.u;                            \
        }                                                                             \
        bf16x8 pa0 = ldv8(&Ps[w][lr][lh * 8]);                                        \
        bf16x8 pa1 = ldv8(&Ps[w][lr][32 + lh * 8]);                                   \
        const bf16* Vc = &Vls[CUR][0];                                                \
        _Pragma("unroll") for (int n = 0; n < 4; ++n) {                               \
            bf16x8 v0 = ldv8(&Vc[(n * 16 + lr) * 64 + ce0]);                          \
            bf16x8 v1 = ldv8(&Vc[(n * 16 + lr) * 64 + ce1]);                          \
            acc_o[n] = MFMA16(pa0, v0, acc_o[n]);                                     \
            acc_o[n] = MFMA16(pa1, v1, acc_o[n]);                                     \
        }                                                                             \
    }

    // -------- main loop: tiles 0..29 (bias tt+2 always valid) --------
    for (int tt = 0; tt < 30; ++tt) {
        const int cur = tt & 1;
        const int ktn = (tt + 1) * 64;
        // [gl_lds(tt+1) x4] into buf cur^1 (all waves done reading it: end-of-(tt-1) bar)
        {
            bf16* Kd = &Kls[cur ^ 1][0];
            bf16* Vd = &Vls[cur ^ 1][0];
            gl_lds16(Kp + (size_t)(ktn + srow0) * HD + sce0, Kd + t * 8);
            gl_lds16(Kp + (size_t)(ktn + srow1) * HD + sce1, Kd + 2048 + t * 8);
            gl_lds16(Vp + (size_t)srow0 * NS + ktn + sce0, Vd + t * 8);
            gl_lds16(Vp + (size_t)srow1 * NS + ktn + sce1, Vd + 2048 + t * 8);
        }
        __builtin_amdgcn_sched_barrier(0);
        // [bias(tt+2) x4]
#pragma unroll
        for (int n = 0; n < 4; ++n) bv2[n] = *(const float4*)(Bp + ktn + 64 + n * 16);
        __builtin_amdgcn_sched_barrier(0);
        // compute tile tt from buf cur, bias bv0
        ATTN_COMPUTE(cur)
        // rotate bias registers (static names, rule #20)
#pragma unroll
        for (int n = 0; n < 4; ++n) { bv0[n] = bv1[n]; bv1[n] = bv2[n]; }
        __builtin_amdgcn_sched_barrier(0);
        asm volatile("s_waitcnt vmcnt(4)" ::: "memory");  // gl_lds(tt+1) done; bias(tt+2) in flight
        __builtin_amdgcn_sched_barrier(0);
        __builtin_amdgcn_s_barrier();
        __builtin_amdgcn_sched_barrier(0);
    }

    // -------- tile 30: stage tile 31, full drain at barrier --------
    {
        const int ktn = 31 * 64;
        bf16* Kd = &Kls[1][0];
        bf16* Vd = &Vls[1][0];
        gl_lds16(Kp + (size_t)(ktn + srow0) * HD + sce0, Kd + t * 8);
        gl_lds16(Kp + (size_t)(ktn + srow1) * HD + sce1, Kd + 2048 + t * 8);
        gl_lds16(Vp + (size_t)srow0 * NS + ktn + sce0, Vd + t * 8);
        gl_lds16(Vp + (size_t)srow1 * NS + ktn + sce1, Vd + 2048 + t * 8);
        __builtin_amdgcn_sched_barrier(0);
        ATTN_COMPUTE(0)
#pragma unroll
        for (int n = 0; n < 4; ++n) bv0[n] = bv1[n];
        __builtin_amdgcn_sched_barrier(0);
        asm volatile("s_waitcnt vmcnt(0)" ::: "memory");
        __builtin_amdgcn_sched_barrier(0);
        __builtin_amdgcn_s_barrier();
        __builtin_amdgcn_sched_barrier(0);
    }
    // -------- tile 31: compute only --------
    ATTN_COMPUTE(1)
#undef ATTN_COMPUTE

    // rowsum for q = qw + (lane&15): reduce over the 4 lh-groups
    rowsum += __shfl_xor(rowsum, 16, 64);
    rowsum += __shfl_xor(rowsum, 32, 64);
    // redistribute: output rows are q = qw + lh*4 + i (held at lane lh*4+i)
    float inv[4];
#pragma unroll
    for (int i = 0; i < 4; ++i) inv[i] = 1.0f / __shfl(rowsum, lh * 4 + i, 64);

    const int b = bh >> 4, h = bh & 15;
#pragma unroll
    for (int n = 0; n < 4; ++n) {
#pragma unroll
        for (int i = 0; i < 4; ++i) {
            const int qrow = qw + lh * 4 + i;
            valsb[(size_t)(b * NS + qrow) * NE + h * HD + n * 16 + lr] =
                __float2bfloat16(acc_o[n][i] * inv[i]);
        }
    }
}

// ---------------- out GEMM: 128x64 tiles (512 blocks = 2/CU) ----------------
__global__ __launch_bounds__(256) void out_gemm(const bf16* __restrict__ A,
                                                const bf16* __restrict__ Bm,
                                                const float* __restrict__ bo,
                                                float* __restrict__ out) {
    __shared__ bf16 As[128 * 32];
    __shared__ bf16 Bs[64 * 32];
    const int brow = blockIdx.x * 128;
    const int bcol = blockIdx.y * 64;
    const int t = threadIdx.x;
    const int w = t >> 6, lane = t & 63;
    const int wr = (w >> 1) * 64, wc = (w & 1) * 32;
    const int lr = lane & 15, lh = lane >> 4;
    const int K = 1024;

    f32x4 acc[4][2];
#pragma unroll
    for (int m = 0; m < 4; ++m)
#pragma unroll
        for (int n = 0; n < 2; ++n) acc[m][n] = (f32x4){0.f, 0.f, 0.f, 0.f};

    const bf16* ga0 = A + (size_t)(brow + (t >> 2)) * K + (t & 3) * 8;
    const bf16* ga1 = A + (size_t)(brow + 64 + (t >> 2)) * K + (t & 3) * 8;
    const bf16* gb0 = Bm + (size_t)(bcol + (t >> 2)) * K + (t & 3) * 8;
    bf16* la0 = As + t * 8;
    bf16* la1 = As + 2048 + t * 8;
    bf16* lb0 = Bs + t * 8;

    for (int kt = 0; kt < K; kt += 32) {
        gl_lds16(ga0 + kt, la0);
        gl_lds16(ga1 + kt, la1);
        gl_lds16(gb0 + kt, lb0);
        __syncthreads();
        bf16x8 af[4], bfv[2];
#pragma unroll
        for (int m = 0; m < 4; ++m) af[m] = ldv8(&As[(wr + m * 16 + lr) * 32 + lh * 8]);
#pragma unroll
        for (int n = 0; n < 2; ++n) bfv[n] = ldv8(&Bs[(wc + n * 16 + lr) * 32 + lh * 8]);
#pragma unroll
        for (int m = 0; m < 4; ++m)
#pragma unroll
            for (int n = 0; n < 2; ++n) acc[m][n] = MFMA16(af[m], bfv[n], acc[m][n]);
        __syncthreads();
    }

#pragma unroll
    for (int n = 0; n < 2; ++n) {
        const int col = bcol + wc + n * 16 + lr;
        const float bv = bo[col];
#pragma unroll
        for (int m = 0; m < 4; ++m) {
            const int row0 = brow + wr + m * 16 + lh * 4;
#pragma unroll
            for (int i = 0; i < 4; ++i) out[(size_t)(row0 + i) * NE + col] = acc[m][n][i] + bv;
        }
    }
}

extern "C" void kernel_launch(void* const* d_in, const int* in_sizes, int n_in,
                              void* d_out, int out_size, void* d_ws, size_t ws_size,
                              hipStream_t stream) {
    const float* x = (const float*)d_in[0];
    const float* attn_bias = (const float*)d_in[1];
    const float* Wqkv = (const float*)d_in[2];
    const float* bqkv = (const float*)d_in[3];
    const float* Wo = (const float*)d_in[4];
    const float* bo = (const float*)d_in[5];
    float* out = (float*)d_out;

    char* ws = (char*)d_ws;
    bf16* xb = (bf16*)(ws);                      // 8 MiB  [4096,1024]
    bf16* Wqkvb = (bf16*)(ws + (8u << 20));      // 6 MiB  [3072,1024]
    bf16* Wob = (bf16*)(ws + (14u << 20));       // 2 MiB  [1024,1024]
    bf16* Qb = (bf16*)(ws + (16u << 20));        // 8 MiB  [B,H,S,HD]
    bf16* Kb = (bf16*)(ws + (24u << 20));        // 8 MiB  [B,H,S,HD]
    bf16* Vtb = (bf16*)(ws + (32u << 20));       // 8 MiB  [B,H,HD,S]
    bf16* valsb = (bf16*)(ws + (40u << 20));     // 8 MiB  [B,S,H,HD]

    // merged casts (1 launch)
    cast3_k<<<8192, 256, 0, stream>>>(x, Wqkv, Wo, xb, Wqkvb, Wob);

    // QKV projection
    qkv_gemm<<<dim3(32, 24), 256, 0, stream>>>(xb, Wqkvb, bqkv, Qb, Kb, Vtb);

    // fused attention (1-D grid, XCD swizzle inside)
    attn_k<<<dim3(1024), 256, 0, stream>>>(Qb, Kb, Vtb, attn_bias, valsb);

    // output projection
    out_gemm<<<dim3(32, 16), 256, 0, stream>>>(valsb, Wob, bo, out);
}

// Round 8
// 211.950 us; speedup vs baseline: 1.7216x; 1.1580x over previous
//
#include <hip/hip_runtime.h>
#include <hip/hip_bf16.h>

#define NB 2
#define NS 2048
#define NE 1024
#define NH 16
#define HD 64

typedef __hip_bfloat16 bf16;
typedef __attribute__((ext_vector_type(8))) short bf16x8;
typedef __attribute__((ext_vector_type(4))) float f32x4;

typedef __attribute__((address_space(3))) void* lds_p;
typedef const __attribute__((address_space(1))) void* glb_p;

#define MFMA16(a, b, c) __builtin_amdgcn_mfma_f32_16x16x32_bf16((a), (b), (c), 0, 0, 0)

__device__ __forceinline__ void gl_lds16(const void* g, void* l) {
    __builtin_amdgcn_global_load_lds((glb_p)g, (lds_p)l, 16, 0, 0);
}

__device__ __forceinline__ bf16x8 ldv8(const bf16* p) { return *(const bf16x8*)p; }

// ---------------- merged cast f32 -> bf16 (vectorized, 1 launch) ----------------
__global__ __launch_bounds__(256) void cast3_k(const float* __restrict__ x,
                                               const float* __restrict__ wqkv,
                                               const float* __restrict__ wo,
                                               bf16* __restrict__ xb,
                                               bf16* __restrict__ wqkvb,
                                               bf16* __restrict__ wob) {
    const int n_x = NB * NS * NE / 4;
    const int n_q = 3 * NE * NE / 4;
    const int n_o = NE * NE / 4;
    int i = blockIdx.x * 256 + threadIdx.x;
    const float* in;
    bf16* out;
    int j;
    if (i < n_x) {
        in = x; out = xb; j = i;
    } else if (i < n_x + n_q) {
        in = wqkv; out = wqkvb; j = i - n_x;
    } else if (i < n_x + n_q + n_o) {
        in = wo; out = wob; j = i - n_x - n_q;
    } else {
        return;
    }
    float4 v = ((const float4*)in)[j];
    union { ushort4 u; bf16 b[4]; } pk;
    pk.b[0] = __float2bfloat16(v.x);
    pk.b[1] = __float2bfloat16(v.y);
    pk.b[2] = __float2bfloat16(v.z);
    pk.b[3] = __float2bfloat16(v.w);
    ((ushort4*)out)[j] = pk.u;
}

// ---------------- QKV GEMM: C[t,f] = sum_e x[t,e] * Wqkv[f,e] + bqkv[f] ----------------
__global__ __launch_bounds__(256) void qkv_gemm(const bf16* __restrict__ A,
                                                const bf16* __restrict__ Bm,
                                                const float* __restrict__ bqkv,
                                                bf16* __restrict__ Qb, bf16* __restrict__ Kb,
                                                bf16* __restrict__ Vtb) {
    __shared__ bf16 As[128 * 32];
    __shared__ bf16 Bs[128 * 32];
    const int brow = blockIdx.x * 128;
    const int bcol = blockIdx.y * 128;
    const int t = threadIdx.x;
    const int w = t >> 6, lane = t & 63;
    const int wr = (w >> 1) * 64, wc = (w & 1) * 64;
    const int lr = lane & 15, lh = lane >> 4;
    const int K = 1024;

    f32x4 acc[4][4];
#pragma unroll
    for (int m = 0; m < 4; ++m)
#pragma unroll
        for (int n = 0; n < 4; ++n) acc[m][n] = (f32x4){0.f, 0.f, 0.f, 0.f};

    const bf16* ga0 = A + (size_t)(brow + (t >> 2)) * K + (t & 3) * 8;
    const bf16* ga1 = A + (size_t)(brow + 64 + (t >> 2)) * K + (t & 3) * 8;
    const bf16* gb0 = Bm + (size_t)(bcol + (t >> 2)) * K + (t & 3) * 8;
    const bf16* gb1 = Bm + (size_t)(bcol + 64 + (t >> 2)) * K + (t & 3) * 8;
    bf16* la0 = As + t * 8;
    bf16* la1 = As + 2048 + t * 8;
    bf16* lb0 = Bs + t * 8;
    bf16* lb1 = Bs + 2048 + t * 8;

    for (int kt = 0; kt < K; kt += 32) {
        gl_lds16(ga0 + kt, la0);
        gl_lds16(ga1 + kt, la1);
        gl_lds16(gb0 + kt, lb0);
        gl_lds16(gb1 + kt, lb1);
        __syncthreads();
        bf16x8 af[4], bfv[4];
#pragma unroll
        for (int m = 0; m < 4; ++m) af[m] = ldv8(&As[(wr + m * 16 + lr) * 32 + lh * 8]);
#pragma unroll
        for (int n = 0; n < 4; ++n) bfv[n] = ldv8(&Bs[(wc + n * 16 + lr) * 32 + lh * 8]);
#pragma unroll
        for (int m = 0; m < 4; ++m)
#pragma unroll
            for (int n = 0; n < 4; ++n) acc[m][n] = MFMA16(af[m], bfv[n], acc[m][n]);
        __syncthreads();
    }

    // epilogue: f -> (h, which, d); which: 0=Q 1=K 2=V
#pragma unroll
    for (int n = 0; n < 4; ++n) {
        const int col = bcol + wc + n * 16 + lr;
        const int h = col / 192;
        const int r = col - h * 192;
        const int wh = r >> 6;
        const int d = r & 63;
        const float bq = bqkv[col];
#pragma unroll
        for (int m = 0; m < 4; ++m) {
            const int row0 = brow + wr + m * 16 + lh * 4;  // token base; i adds 0..3
            const int b = row0 >> 11;
            const int s0 = row0 & 2047;
            const size_t hb = (size_t)(b * NH + h) * (NS * HD);
            if (wh == 2) {
                alignas(8) bf16 tmp[4];
#pragma unroll
                for (int i = 0; i < 4; ++i) tmp[i] = __float2bfloat16(acc[m][n][i] + bq);
                *(ushort4*)(Vtb + hb + (size_t)d * NS + s0) = *(const ushort4*)tmp;
            } else {
                bf16* dst = (wh == 0 ? Qb : Kb) + hb + (size_t)s0 * HD + d;
#pragma unroll
                for (int i = 0; i < 4; ++i) dst[(size_t)i * HD] = __float2bfloat16(acc[m][n][i] + bq);
            }
        }
    }
}

// ---------------- fused attention: LDS K/V + counted vmcnt + 4 blocks/CU ----------------
// 1024 blocks (XCD swizzle), 4 waves x 16 q-rows, one bh per block.
// LDS exactly 40KB (Ps XOR-swizzled, no pad) -> 4 blocks/CU: all 1024 blocks
// co-resident (no tail), 16 waves/CU of outstanding bias requests.
// Per tile: [gl_lds(tt+1) x4] | compute(tt) | [bias(tt+2) x4 into just-freed set] |
// vmcnt(4) | s_barrier.  Oldest-first drain forces bias(tt+1)+gl_lds(tt+1) complete,
// keeps bias(tt+2) in flight - the bias HBM stream is never drained.
__global__ __launch_bounds__(256, 4) void attn_k(const bf16* __restrict__ Qb,
                                                 const bf16* __restrict__ Kb,
                                                 const bf16* __restrict__ Vtb,
                                                 const float* __restrict__ bias,
                                                 bf16* __restrict__ valsb) {
    const int L = blockIdx.x;
    const int xcd = L & 7, kk = L >> 3;
    const int bh = (xcd << 2) | (kk >> 5);   // 4 bh per XCD (K/V L2-resident)
    const int q0 = (kk & 31) * 64;
    const int t = threadIdx.x;
    const int w = t >> 6, lane = t & 63;
    const int lr = lane & 15, lh = lane >> 4;

    __shared__ bf16 Kls[2][64 * 64];   // 16 KB
    __shared__ bf16 Vls[2][64 * 64];   // 16 KB
    __shared__ bf16 Ps[4][16 * 64];    // 8 KB, XOR-swizzled in 16B units

    const bf16* Qp = Qb + (size_t)bh * NS * HD;
    const bf16* Kp = Kb + (size_t)bh * NS * HD;
    const bf16* Vp = Vtb + (size_t)bh * HD * NS;

    const int qw = q0 + w * 16;
    bf16x8 qf0 = ldv8(&Qp[(qw + lr) * HD + lh * 8]);
    bf16x8 qf1 = ldv8(&Qp[(qw + lr) * HD + 32 + lh * 8]);

    // per-lane bias base: row q = qw+lr, col base lh*4
    const float* Bp = bias + (size_t)bh * NS * NS + (size_t)(qw + lr) * NS + lh * 4;

    // staging geometry (XOR-swizzled source, linear LDS dest; rule #21)
    const int srow0 = t >> 3;
    const int sce0 = ((t & 7) * 8) ^ ((srow0 & 7) << 3);
    const int srow1 = srow0 + 32;
    const int sce1 = ((t & 7) * 8) ^ ((srow1 & 7) << 3);

    f32x4 acc_o[4];
    float rowsum = 0.f;
#pragma unroll
    for (int n = 0; n < 4; ++n) acc_o[n] = (f32x4){0.f, 0.f, 0.f, 0.f};

    const float C1 = 0.18033688011112042f;  // 0.125 * log2(e)
    const float C2 = 7.2134752044448170f;   // 5 * log2(e)

    // read-side swizzled column offsets (K/V: row = n*16+lr => row&7 = lr&7)
    const int rswz = (lr & 7) << 3;
    const int ce0 = (lh * 8) ^ rswz;
    const int ce1 = (32 + lh * 8) ^ rswz;
    // Ps swizzle: 16B unit index XORed with lr&7 (write ushort4 stays in-unit)
    const int pswz = (lr & 7) << 3;

    // -------- prologue: [gl_lds(0) x4] | bias(0)->bvA | bias(1)->bvB | vmcnt(8) | bar
    gl_lds16(Kp + (size_t)srow0 * HD + sce0, &Kls[0][t * 8]);
    gl_lds16(Kp + (size_t)srow1 * HD + sce1, &Kls[0][2048 + t * 8]);
    gl_lds16(Vp + (size_t)srow0 * NS + sce0, &Vls[0][t * 8]);
    gl_lds16(Vp + (size_t)srow1 * NS + sce1, &Vls[0][2048 + t * 8]);
    __builtin_amdgcn_sched_barrier(0);
    float4 bvA[4], bvB[4];
#pragma unroll
    for (int n = 0; n < 4; ++n) bvA[n] = *(const float4*)(Bp + n * 16);
    __builtin_amdgcn_sched_barrier(0);
#pragma unroll
    for (int n = 0; n < 4; ++n) bvB[n] = *(const float4*)(Bp + 64 + n * 16);
    __builtin_amdgcn_sched_barrier(0);
    asm volatile("s_waitcnt vmcnt(8)" ::: "memory");
    __builtin_amdgcn_sched_barrier(0);
    __builtin_amdgcn_s_barrier();
    __builtin_amdgcn_sched_barrier(0);

#define ATTN_COMPUTE(CUR, BV)                                                         \
    {                                                                                 \
        const bf16* Kc = &Kls[CUR][0];                                                \
        f32x4 s[4];                                                                   \
        _Pragma("unroll") for (int n = 0; n < 4; ++n) {                               \
            bf16x8 k0 = ldv8(&Kc[(n * 16 + lr) * 64 + ce0]);                          \
            bf16x8 k1 = ldv8(&Kc[(n * 16 + lr) * 64 + ce1]);                          \
            s[n] = (f32x4){0.f, 0.f, 0.f, 0.f};                                       \
            s[n] = MFMA16(k0, qf0, s[n]);                                             \
            s[n] = MFMA16(k1, qf1, s[n]);                                             \
        }                                                                             \
        _Pragma("unroll") for (int n = 0; n < 4; ++n) {                               \
            union { ushort4 u; bf16 b[4]; } pk;                                       \
            _Pragma("unroll") for (int i = 0; i < 4; ++i) {                           \
                float bb = (i == 0   ? BV[n].x                                        \
                            : i == 1 ? BV[n].y                                        \
                            : i == 2 ? BV[n].z                                        \
                                     : BV[n].w);                                      \
                float xv = (s[n][i] + bb) * C1;                                       \
                xv = fminf(fmaxf(xv, -C2), C2);                                       \
                float p = exp2f(xv);                                                  \
                rowsum += p;                                                          \
                pk.b[i] = __float2bfloat16(p);                                        \
            }                                                                         \
            *(ushort4*)&Ps[w][lr * 64 + ((n * 16 + lh * 4) ^ pswz)] = pk.u;           \
        }                                                                             \
        bf16x8 pa0 = ldv8(&Ps[w][lr * 64 + ((lh * 8) ^ pswz)]);                       \
        bf16x8 pa1 = ldv8(&Ps[w][lr * 64 + (((32 + lh * 8)) ^ pswz)]);                \
        const bf16* Vc = &Vls[CUR][0];                                                \
        _Pragma("unroll") for (int n = 0; n < 4; ++n) {                               \
            bf16x8 v0 = ldv8(&Vc[(n * 16 + lr) * 64 + ce0]);                          \
            bf16x8 v1 = ldv8(&Vc[(n * 16 + lr) * 64 + ce1]);                          \
            acc_o[n] = MFMA16(pa0, v0, acc_o[n]);                                     \
            acc_o[n] = MFMA16(pa1, v1, acc_o[n]);                                     \
        }                                                                             \
    }

    // one tile step: stage tile at KTN into buf CUR^1, compute tile CUR from bias BV,
    // then refill BV with bias(KTN+64) (consumed two tiles later).
#define TILESTEP(CUR, BV, KTN)                                                        \
    {                                                                                 \
        bf16* Kd = &Kls[(CUR) ^ 1][0];                                                \
        bf16* Vd = &Vls[(CUR) ^ 1][0];                                                \
        gl_lds16(Kp + (size_t)((KTN) + srow0) * HD + sce0, Kd + t * 8);               \
        gl_lds16(Kp + (size_t)((KTN) + srow1) * HD + sce1, Kd + 2048 + t * 8);        \
        gl_lds16(Vp + (size_t)srow0 * NS + (KTN) + sce0, Vd + t * 8);                 \
        gl_lds16(Vp + (size_t)srow1 * NS + (KTN) + sce1, Vd + 2048 + t * 8);          \
        __builtin_amdgcn_sched_barrier(0);                                            \
        ATTN_COMPUTE(CUR, BV)                                                         \
        __builtin_amdgcn_sched_barrier(0);                                            \
        _Pragma("unroll") for (int n = 0; n < 4; ++n)                                 \
            BV[n] = *(const float4*)(Bp + (KTN) + 64 + n * 16);                       \
        __builtin_amdgcn_sched_barrier(0);                                            \
        asm volatile("s_waitcnt vmcnt(4)" ::: "memory");                              \
        __builtin_amdgcn_sched_barrier(0);                                            \
        __builtin_amdgcn_s_barrier();                                                 \
        __builtin_amdgcn_sched_barrier(0);                                            \
    }

    // -------- main loop: tiles 0..29, unrolled x2 for static bias-set naming --------
    for (int it = 0; it < 15; ++it) {
        const int tt = it * 2;
        TILESTEP(0, bvA, (tt + 1) * 64)
        TILESTEP(1, bvB, (tt + 2) * 64)
    }

    // -------- tile 30: stage tile 31, full drain at barrier --------
    {
        const int ktn = 31 * 64;
        bf16* Kd = &Kls[1][0];
        bf16* Vd = &Vls[1][0];
        gl_lds16(Kp + (size_t)(ktn + srow0) * HD + sce0, Kd + t * 8);
        gl_lds16(Kp + (size_t)(ktn + srow1) * HD + sce1, Kd + 2048 + t * 8);
        gl_lds16(Vp + (size_t)srow0 * NS + ktn + sce0, Vd + t * 8);
        gl_lds16(Vp + (size_t)srow1 * NS + ktn + sce1, Vd + 2048 + t * 8);
        __builtin_amdgcn_sched_barrier(0);
        ATTN_COMPUTE(0, bvA)
        __builtin_amdgcn_sched_barrier(0);
        asm volatile("s_waitcnt vmcnt(0)" ::: "memory");
        __builtin_amdgcn_sched_barrier(0);
        __builtin_amdgcn_s_barrier();
        __builtin_amdgcn_sched_barrier(0);
    }
    // -------- tile 31: compute only --------
    ATTN_COMPUTE(1, bvB)
#undef TILESTEP
#undef ATTN_COMPUTE

    // rowsum for q = qw + (lane&15): reduce over the 4 lh-groups
    rowsum += __shfl_xor(rowsum, 16, 64);
    rowsum += __shfl_xor(rowsum, 32, 64);
    // redistribute: output rows are q = qw + lh*4 + i (held at lane lh*4+i)
    float inv[4];
#pragma unroll
    for (int i = 0; i < 4; ++i) inv[i] = 1.0f / __shfl(rowsum, lh * 4 + i, 64);

    const int b = bh >> 4, h = bh & 15;
#pragma unroll
    for (int n = 0; n < 4; ++n) {
#pragma unroll
        for (int i = 0; i < 4; ++i) {
            const int qrow = qw + lh * 4 + i;
            valsb[(size_t)(b * NS + qrow) * NE + h * HD + n * 16 + lr] =
                __float2bfloat16(acc_o[n][i] * inv[i]);
        }
    }
}

// ---------------- out GEMM: 128x64 tiles (512 blocks = 2/CU) ----------------
__global__ __launch_bounds__(256) void out_gemm(const bf16* __restrict__ A,
                                                const bf16* __restrict__ Bm,
                                                const float* __restrict__ bo,
                                                float* __restrict__ out) {
    __shared__ bf16 As[128 * 32];
    __shared__ bf16 Bs[64 * 32];
    const int brow = blockIdx.x * 128;
    const int bcol = blockIdx.y * 64;
    const int t = threadIdx.x;
    const int w = t >> 6, lane = t & 63;
    const int wr = (w >> 1) * 64, wc = (w & 1) * 32;
    const int lr = lane & 15, lh = lane >> 4;
    const int K = 1024;

    f32x4 acc[4][2];
#pragma unroll
    for (int m = 0; m < 4; ++m)
#pragma unroll
        for (int n = 0; n < 2; ++n) acc[m][n] = (f32x4){0.f, 0.f, 0.f, 0.f};

    const bf16* ga0 = A + (size_t)(brow + (t >> 2)) * K + (t & 3) * 8;
    const bf16* ga1 = A + (size_t)(brow + 64 + (t >> 2)) * K + (t & 3) * 8;
    const bf16* gb0 = Bm + (size_t)(bcol + (t >> 2)) * K + (t & 3) * 8;
    bf16* la0 = As + t * 8;
    bf16* la1 = As + 2048 + t * 8;
    bf16* lb0 = Bs + t * 8;

    for (int kt = 0; kt < K; kt += 32) {
        gl_lds16(ga0 + kt, la0);
        gl_lds16(ga1 + kt, la1);
        gl_lds16(gb0 + kt, lb0);
        __syncthreads();
        bf16x8 af[4], bfv[2];
#pragma unroll
        for (int m = 0; m < 4; ++m) af[m] = ldv8(&As[(wr + m * 16 + lr) * 32 + lh * 8]);
#pragma unroll
        for (int n = 0; n < 2; ++n) bfv[n] = ldv8(&Bs[(wc + n * 16 + lr) * 32 + lh * 8]);
#pragma unroll
        for (int m = 0; m < 4; ++m)
#pragma unroll
            for (int n = 0; n < 2; ++n) acc[m][n] = MFMA16(af[m], bfv[n], acc[m][n]);
        __syncthreads();
    }

#pragma unroll
    for (int n = 0; n < 2; ++n) {
        const int col = bcol + wc + n * 16 + lr;
        const float bv = bo[col];
#pragma unroll
        for (int m = 0; m < 4; ++m) {
            const int row0 = brow + wr + m * 16 + lh * 4;
#pragma unroll
            for (int i = 0; i < 4; ++i) out[(size_t)(row0 + i) * NE + col] = acc[m][n][i] + bv;
        }
    }
}

extern "C" void kernel_launch(void* const* d_in, const int* in_sizes, int n_in,
                              void* d_out, int out_size, void* d_ws, size_t ws_size,
                              hipStream_t stream) {
    const float* x = (const float*)d_in[0];
    const float* attn_bias = (const float*)d_in[1];
    const float* Wqkv = (const float*)d_in[2];
    const float* bqkv = (const float*)d_in[3];
    const float* Wo = (const float*)d_in[4];
    const float* bo = (const float*)d_in[5];
    float* out = (float*)d_out;

    char* ws = (char*)d_ws;
    bf16* xb = (bf16*)(ws);                      // 8 MiB  [4096,1024]
    bf16* Wqkvb = (bf16*)(ws + (8u << 20));      // 6 MiB  [3072,1024]
    bf16* Wob = (bf16*)(ws + (14u << 20));       // 2 MiB  [1024,1024]
    bf16* Qb = (bf16*)(ws + (16u << 20));        // 8 MiB  [B,H,S,HD]
    bf16* Kb = (bf16*)(ws + (24u << 20));        // 8 MiB  [B,H,S,HD]
    bf16* Vtb = (bf16*)(ws + (32u << 20));       // 8 MiB  [B,H,HD,S]
    bf16* valsb = (bf16*)(ws + (40u << 20));     // 8 MiB  [B,S,H,HD]

    // merged casts (1 launch)
    cast3_k<<<8192, 256, 0, stream>>>(x, Wqkv, Wo, xb, Wqkvb, Wob);

    // QKV projection
    qkv_gemm<<<dim3(32, 24), 256, 0, stream>>>(xb, Wqkvb, bqkv, Qb, Kb, Vtb);

    // fused attention (1-D grid, XCD swizzle inside)
    attn_k<<<dim3(1024), 256, 0, stream>>>(Qb, Kb, Vtb, attn_bias, valsb);

    // output projection
    out_gemm<<<dim3(32, 16), 256, 0, stream>>>(valsb, Wob, bo, out);
}